// Round 3
// baseline (4561.376 us; speedup 1.0000x reference)
//
#include <hip/hip_runtime.h>
#include <hip/hip_fp16.h>

// RNAGNN round 3: bucketed-LDS aggregation, fp16 message table, fused heads.
//   z = dinv ⊙ h  (fp16, 32B/node)       [layer0: z0 = dinv ⊙ (x@W_in)]
//   agg[i] = Σ_{e: dst=i} z[src] + z[i]  (LDS fp32 accumulate, bucket of 128 nodes/block)
//   conv out = (dinv ⊙ agg) @ W + b      (matmul AFTER aggregation — commutes)
// Heads share one aggregation (W_sin / W_cos applied in the same epilogue).

#define DIM 16
#define F_IN 64
#define BUCK_SHIFT 7
#define BUCK_SIZE 128
#define MAXB 1600
#define BIN_CHUNK 16384

// ---------------- degree + dinv ----------------

__global__ void deg_kernel(const int* __restrict__ dst, int* __restrict__ deg, int E) {
    int e = blockIdx.x * blockDim.x + threadIdx.x;
    if (e < E) atomicAdd(&deg[dst[e]], 1);
}

__global__ void dinv_kernel(const int* __restrict__ deg, float* __restrict__ dinv, int n) {
    int i = blockIdx.x * blockDim.x + threadIdx.x;
    if (i < n) dinv[i] = rsqrtf((float)(deg[i] + 1));  // +1 = self loop
}

// per-bucket edge counts from deg (no extra edge pass)
__global__ void ghist_kernel(const int* __restrict__ deg, int* __restrict__ ghist, int N) {
    __shared__ int sd[BUCK_SIZE];
    int b = blockIdx.x, t = threadIdx.x;
    int i = (b << BUCK_SHIFT) + t;
    sd[t] = (i < N) ? deg[i] : 0;
    __syncthreads();
    for (int st = 64; st > 0; st >>= 1) {
        if (t < st) sd[t] += sd[t + st];
        __syncthreads();
    }
    if (t == 0) ghist[b] = sd[0];
}

// exclusive scan of ghist (nb <= 1792) -> boff, cursor
__global__ void scan_kernel(const int* __restrict__ ghist, int* __restrict__ boff,
                            int* __restrict__ cursor, int nb, int E) {
    __shared__ int sd[256];
    int t = threadIdx.x;
    const int CH = 7;
    int v[CH];
    int s = 0;
    for (int j = 0; j < CH; ++j) {
        int i = t * CH + j;
        v[j] = (i < nb) ? ghist[i] : 0;
        s += v[j];
    }
    sd[t] = s;
    __syncthreads();
    for (int off = 1; off < 256; off <<= 1) {
        int u = (t >= off) ? sd[t - off] : 0;
        __syncthreads();
        sd[t] += u;
        __syncthreads();
    }
    int excl = (t > 0) ? sd[t - 1] : 0;
    for (int j = 0; j < CH; ++j) {
        int i = t * CH + j;
        if (i < nb) { boff[i] = excl; cursor[i] = excl; excl += v[j]; }
    }
    if (t == 255) boff[nb] = E;
}

// bin edges into dst-range buckets; packed = src | (local_dst << 18)
__global__ void bin_kernel(const int* __restrict__ src, const int* __restrict__ dst,
                           int* __restrict__ cursor, unsigned* __restrict__ packed,
                           int E, int nb) {
    __shared__ int lh[MAXB];
    int t = threadIdx.x;
    int base = blockIdx.x * BIN_CHUNK;
    int end = min(base + BIN_CHUNK, E);
    for (int i = t; i < nb; i += 256) lh[i] = 0;
    __syncthreads();
    for (int e = base + t; e < end; e += 256) atomicAdd(&lh[dst[e] >> BUCK_SHIFT], 1);
    __syncthreads();
    for (int b = t; b < nb; b += 256) {
        int c = lh[b];
        lh[b] = c ? atomicAdd(&cursor[b], c) : 0;
    }
    __syncthreads();
    for (int e = base + t; e < end; e += 256) {
        int d = dst[e];
        int b = d >> BUCK_SHIFT;
        int pos = atomicAdd(&lh[b], 1);
        packed[pos] = (unsigned)src[e] | ((unsigned)(d & (BUCK_SIZE - 1)) << 18);
    }
}

// ---------------- z0 = dinv * (x @ W_in) as fp16 ----------------

__global__ void z0_kernel(const float* __restrict__ x, const float* __restrict__ W,
                          const float* __restrict__ dinv, __half* __restrict__ z, int n) {
    __shared__ float sW[F_IN * DIM];
    int t = threadIdx.x;
    for (int i = t; i < F_IN * DIM; i += 256) sW[i] = W[i];
    __syncthreads();
    int idx = blockIdx.x * 256 + t;
    if (idx >= n * 8) return;
    int node = idx >> 3, f0 = (idx & 7) * 2;
    const float* xr = x + (size_t)node * F_IN;
    float a0 = 0.f, a1 = 0.f;
#pragma unroll
    for (int k = 0; k < F_IN; ++k) {
        float xv = xr[k];
        a0 += xv * sW[k * DIM + f0];
        a1 += xv * sW[k * DIM + f0 + 1];
    }
    float di = dinv[node];
    *(__half2*)(z + (size_t)node * DIM + f0) = __floats2half2_rn(di * a0, di * a1);
}

// ---------------- aggregation + fused epilogue ----------------
// mode 0: zout = dinv*( dinv*(acc+z_self) + b )            (layer 0, identity W)
// mode 1: o1   = (dinv*(acc+z_self)) @ Wa + ba             (pre-BN, fp32)
// mode 3: o1   = relu((dinv*(acc+z_self)) @ Wa + ba)       (sin head)
//         o2   = relu((dinv*(acc+z_self)) @ Wb + bb)       (cos head)

__launch_bounds__(256)
__global__ void agg_kernel(const unsigned* __restrict__ packed, const int* __restrict__ boff,
                           const __half* __restrict__ z, const float* __restrict__ dinv,
                           const float* __restrict__ Wa, const float* __restrict__ Wb,
                           const float* __restrict__ ba, const float* __restrict__ bb,
                           float* __restrict__ o1, float* __restrict__ o2,
                           __half* __restrict__ zout, int N, int mode) {
    __shared__ float acc[BUCK_SIZE * 17];   // stride 17: spreads ds_add banks
    __shared__ float sW[544];               // Wa[256] Wb[256] ba[16] bb[16]
    int t = threadIdx.x;
    int blk = blockIdx.x;
    for (int i = t; i < BUCK_SIZE * 17; i += 256) acc[i] = 0.f;
    if (mode != 0) {
        sW[t] = Wa[t];
        if (mode == 3) sW[256 + t] = Wb[t];
    }
    if (t < 16) {
        sW[512 + t] = ba[t];
        if (mode == 3) sW[528 + t] = bb[t];
    }
    __syncthreads();

    int estart = boff[blk], eend = boff[blk + 1];
    int q = t & 3;                           // 4 lanes per edge, 8B of z each
    for (int e = estart + (t >> 2); e < eend; e += 64) {
        unsigned k = packed[e];
        int s = (int)(k & 0x3FFFFu);
        int ld = (int)(k >> 18);
        const __half2* zp = (const __half2*)(z + ((size_t)s << 4) + (q << 2));
        float2 f0 = __half22float2(zp[0]);
        float2 f1 = __half22float2(zp[1]);
        float* a = &acc[ld * 17 + (q << 2)];
        atomicAdd(a + 0, f0.x);
        atomicAdd(a + 1, f0.y);
        atomicAdd(a + 2, f1.x);
        atomicAdd(a + 3, f1.y);
    }
    __syncthreads();

    int nbase = blk << BUCK_SHIFT;
    int nn = min(BUCK_SIZE, N - nbase);
    if (t < nn) {
        int node = nbase + t;
        float di = dinv[node];
        float r[16];
        const __half2* zs = (const __half2*)(z + ((size_t)node << 4));
#pragma unroll
        for (int j = 0; j < 8; ++j) {
            float2 f = __half22float2(zs[j]);
            r[2 * j]     = di * (acc[t * 17 + 2 * j] + f.x);
            r[2 * j + 1] = di * (acc[t * 17 + 2 * j + 1] + f.y);
        }
        if (mode == 0) {
            __half2* zo = (__half2*)(zout + ((size_t)node << 4));
#pragma unroll
            for (int j = 0; j < 8; ++j) {
                zo[j] = __floats2half2_rn(di * (r[2 * j] + sW[512 + 2 * j]),
                                          di * (r[2 * j + 1] + sW[512 + 2 * j + 1]));
            }
        } else if (mode == 1) {
            float4* op = (float4*)(o1 + ((size_t)node << 4));
#pragma unroll
            for (int j4 = 0; j4 < 4; ++j4) {
                float o[4];
#pragma unroll
                for (int jj = 0; jj < 4; ++jj) {
                    int j = j4 * 4 + jj;
                    float s = sW[512 + j];
#pragma unroll
                    for (int f = 0; f < 16; ++f) s += r[f] * sW[f * 16 + j];
                    o[jj] = s;
                }
                op[j4] = make_float4(o[0], o[1], o[2], o[3]);
            }
        } else {
            float4* os = (float4*)(o1 + ((size_t)node << 4));
            float4* oc = (float4*)(o2 + ((size_t)node << 4));
#pragma unroll
            for (int j4 = 0; j4 < 4; ++j4) {
                float o[4], p[4];
#pragma unroll
                for (int jj = 0; jj < 4; ++jj) {
                    int j = j4 * 4 + jj;
                    float s = sW[512 + j], c = sW[528 + j];
#pragma unroll
                    for (int f = 0; f < 16; ++f) {
                        s += r[f] * sW[f * 16 + j];
                        c += r[f] * sW[256 + f * 16 + j];
                    }
                    o[jj] = fmaxf(s, 0.f);
                    p[jj] = fmaxf(c, 0.f);
                }
                os[j4] = make_float4(o[0], o[1], o[2], o[3]);
                oc[j4] = make_float4(p[0], p[1], p[2], p[3]);
            }
        }
    }
}

// ---------------- BN stats + BN/ReLU (writes next z, fp16) ----------------

__global__ void bnstats_kernel(const float4* __restrict__ hp, float* __restrict__ bnsum, int n4) {
    __shared__ float s1[256 * 4];
    __shared__ float s2[256 * 4];
    int t = threadIdx.x;
    float sx = 0, sy = 0, sz = 0, sw = 0, qx = 0, qy = 0, qz = 0, qw = 0;
    int stride = gridDim.x * 256;   // divisible by 4: q-class fixed per thread
    for (int idx = blockIdx.x * 256 + t; idx < n4; idx += stride) {
        float4 v = hp[idx];
        sx += v.x; sy += v.y; sz += v.z; sw += v.w;
        qx += v.x * v.x; qy += v.y * v.y; qz += v.z * v.z; qw += v.w * v.w;
    }
    s1[t * 4 + 0] = sx; s1[t * 4 + 1] = sy; s1[t * 4 + 2] = sz; s1[t * 4 + 3] = sw;
    s2[t * 4 + 0] = qx; s2[t * 4 + 1] = qy; s2[t * 4 + 2] = qz; s2[t * 4 + 3] = qw;
    __syncthreads();
    for (int st = 128; st >= 4; st >>= 1) {
        if (t < st) {
#pragma unroll
            for (int j = 0; j < 4; ++j) {
                s1[t * 4 + j] += s1[(t + st) * 4 + j];
                s2[t * 4 + j] += s2[(t + st) * 4 + j];
            }
        }
        __syncthreads();
    }
    if (t < 4) {
#pragma unroll
        for (int j = 0; j < 4; ++j) {
            atomicAdd(&bnsum[t * 4 + j], s1[t * 4 + j]);
            atomicAdd(&bnsum[16 + t * 4 + j], s2[t * 4 + j]);
        }
    }
}

__global__ void bn_relu_z_kernel(const float4* __restrict__ hp, const float* __restrict__ bnsum,
                                 const float* __restrict__ gamma, const float* __restrict__ beta,
                                 const float* __restrict__ dinv, __half* __restrict__ z, int n) {
    int idx = blockIdx.x * 256 + threadIdx.x;
    if (idx >= n * 4) return;
    int node = idx >> 2, q = idx & 3;
    float invN = 1.f / (float)n;
    float di = dinv[node];
    float4 v = hp[idx];
    float vv[4] = { v.x, v.y, v.z, v.w };
    float rr[4];
#pragma unroll
    for (int j = 0; j < 4; ++j) {
        int f = q * 4 + j;
        float mean = bnsum[f] * invN;
        float var = fmaxf(bnsum[16 + f] * invN - mean * mean, 0.f);
        rr[j] = di * fmaxf(gamma[f] * (vv[j] - mean) * rsqrtf(var + 1e-5f) + beta[f], 0.f);
    }
    __half2* zo = (__half2*)(z + (size_t)node * DIM + q * 4);
    zo[0] = __floats2half2_rn(rr[0], rr[1]);
    zo[1] = __floats2half2_rn(rr[2], rr[3]);
}

// ---------------- launcher ----------------

extern "C" void kernel_launch(void* const* d_in, const int* in_sizes, int n_in,
                              void* d_out, int out_size, void* d_ws, size_t ws_size,
                              hipStream_t stream) {
    (void)n_in; (void)out_size; (void)ws_size;
    const float* x      = (const float*)d_in[0];
    const int*   edge   = (const int*)d_in[1];
    const float* W_in   = (const float*)d_in[2];
    const float* b_in   = (const float*)d_in[3];
    const float* Ws     = (const float*)d_in[4];
    const float* bs     = (const float*)d_in[5];
    const float* gammas = (const float*)d_in[6];
    const float* betas  = (const float*)d_in[7];
    const float* W_sin  = (const float*)d_in[8];
    const float* b_sin  = (const float*)d_in[9];
    const float* W_cos  = (const float*)d_in[10];
    const float* b_cos  = (const float*)d_in[11];
    float* out = (float*)d_out;

    const int N = in_sizes[0] / F_IN;          // 200000
    const int E = in_sizes[1] / 2;             // 6400000
    const int L = in_sizes[4] / (DIM * DIM);   // 4
    const int nb = (N + BUCK_SIZE - 1) >> BUCK_SHIFT;   // 1563
    const int* src = edge;
    const int* dst = edge + E;

    char* ws = (char*)d_ws;
    size_t off = 0;
    auto alloc = [&](size_t bytes) { char* p = ws + off; off += (bytes + 15) & ~size_t(15); return p; };
    int*      deg    = (int*)alloc((size_t)N * 4);
    float*    dinv   = (float*)alloc((size_t)N * 4);
    int*      ghist  = (int*)alloc((size_t)nb * 4);
    int*      boff   = (int*)alloc((size_t)(nb + 1) * 4);
    int*      cursor = (int*)alloc((size_t)nb * 4);
    unsigned* packed = (unsigned*)alloc((size_t)E * 4);
    __half*   zA     = (__half*)alloc((size_t)N * DIM * 2);
    __half*   zB     = (__half*)alloc((size_t)N * DIM * 2);
    float*    hp     = (float*)alloc((size_t)N * DIM * 4);
    float*    bnsum  = (float*)alloc(32 * 4 * (size_t)L);

    hipMemsetAsync(deg, 0, (size_t)N * 4, stream);
    hipMemsetAsync(bnsum, 0, 32 * 4 * (size_t)L, stream);

    deg_kernel<<<(E + 255) / 256, 256, 0, stream>>>(dst, deg, E);
    dinv_kernel<<<(N + 255) / 256, 256, 0, stream>>>(deg, dinv, N);
    ghist_kernel<<<nb, 128, 0, stream>>>(deg, ghist, N);
    scan_kernel<<<1, 256, 0, stream>>>(ghist, boff, cursor, nb, E);
    bin_kernel<<<(E + BIN_CHUNK - 1) / BIN_CHUNK, 256, 0, stream>>>(src, dst, cursor, packed, E, nb);

    // layer 0: z0 = dinv*(x@W_in), then aggregate with identity-W epilogue
    z0_kernel<<<(N * 8 + 255) / 256, 256, 0, stream>>>(x, W_in, dinv, zA, N);
    agg_kernel<<<nb, 256, 0, stream>>>(packed, boff, zA, dinv,
                                       nullptr, nullptr, b_in, nullptr,
                                       nullptr, nullptr, zB, N, 0);
    __half* zc = zB;
    __half* zn = zA;

    for (int l = 0; l < L; ++l) {
        agg_kernel<<<nb, 256, 0, stream>>>(packed, boff, zc, dinv,
                                           Ws + l * DIM * DIM, nullptr,
                                           bs + l * DIM, nullptr,
                                           hp, nullptr, nullptr, N, 1);
        bnstats_kernel<<<1024, 256, 0, stream>>>((const float4*)hp, bnsum + 32 * l, N * 4);
        bn_relu_z_kernel<<<(N * 4 + 255) / 256, 256, 0, stream>>>(
            (const float4*)hp, bnsum + 32 * l, gammas + l * DIM, betas + l * DIM,
            dinv, zn, N);
        __half* tmp = zc; zc = zn; zn = tmp;
    }

    // heads: one shared aggregation, dual-matmul epilogue straight into d_out
    agg_kernel<<<nb, 256, 0, stream>>>(packed, boff, zc, dinv,
                                       W_sin, W_cos, b_sin, b_cos,
                                       out, out + (size_t)N * DIM, nullptr, N, 3);
}

// Round 4
// 1859.244 us; speedup vs baseline: 2.4534x; 2.4534x over previous
//
#include <hip/hip_runtime.h>
#include <hip/hip_fp16.h>

// RNAGNN round 4: CSR gather (high TLP) + fp16 message table + cheap 2-level CSR build.
//   z = dinv ⊙ h (fp16);  r[i] = dinv[i]*(z[i] + Σ_{e:dst=i} z[src]);  out = r @ W + b
// 6 aggregation passes: layer0(identity W), 4 hidden (matmul+BN-stats in epilogue),
// 1 shared for both heads (dual matmul + ReLU into d_out).

#define DIM 16
#define F_IN 64
#define BUCK_SHIFT 8
#define BUCK_SIZE 256
#define MAXB 800
#define BIN_CHUNK 4096

// ---------------- degree + dinv ----------------

__global__ void deg_kernel(const int* __restrict__ dst, int* __restrict__ deg, int E) {
    int e = blockIdx.x * blockDim.x + threadIdx.x;
    if (e < E) atomicAdd(&deg[dst[e]], 1);
}

__global__ void dinv_kernel(const int* __restrict__ deg, float* __restrict__ dinv, int n) {
    int i = blockIdx.x * blockDim.x + threadIdx.x;
    if (i < n) dinv[i] = rsqrtf((float)(deg[i] + 1));  // +1 = self loop
}

// per-bucket edge counts (from deg; no edge pass)
__global__ void ghist_kernel(const int* __restrict__ deg, int* __restrict__ ghist, int N) {
    __shared__ int sd[BUCK_SIZE];
    int b = blockIdx.x, t = threadIdx.x;
    int i = (b << BUCK_SHIFT) + t;
    sd[t] = (i < N) ? deg[i] : 0;
    __syncthreads();
    for (int st = 128; st > 0; st >>= 1) {
        if (t < st) sd[t] += sd[t + st];
        __syncthreads();
    }
    if (t == 0) ghist[b] = sd[0];
}

// exclusive scan of ghist (nb <= 1024) -> boff, cursor
__global__ void scan_kernel(const int* __restrict__ ghist, int* __restrict__ boff,
                            int* __restrict__ cursor, int nb, int E) {
    __shared__ int sd[256];
    int t = threadIdx.x;
    const int CH = 4;
    int v[CH];
    int s = 0;
#pragma unroll
    for (int j = 0; j < CH; ++j) {
        int i = t * CH + j;
        v[j] = (i < nb) ? ghist[i] : 0;
        s += v[j];
    }
    sd[t] = s;
    __syncthreads();
    for (int off = 1; off < 256; off <<= 1) {
        int u = (t >= off) ? sd[t - off] : 0;
        __syncthreads();
        sd[t] += u;
        __syncthreads();
    }
    int excl = (t > 0) ? sd[t - 1] : 0;
#pragma unroll
    for (int j = 0; j < CH; ++j) {
        int i = t * CH + j;
        if (i < nb) { boff[i] = excl; cursor[i] = excl; excl += v[j]; }
    }
    if (t == 255) boff[nb] = E;
}

// pass A: bin edges into dst-range buckets; packed = src | (local_dst << 18)
__global__ void bin_kernel(const int* __restrict__ src, const int* __restrict__ dst,
                           int* __restrict__ cursor, unsigned* __restrict__ packed,
                           int E, int nb) {
    __shared__ int lh[MAXB];
    int t = threadIdx.x;
    int base = blockIdx.x * BIN_CHUNK;
    int end = min(base + BIN_CHUNK, E);
    for (int i = t; i < nb; i += 256) lh[i] = 0;
    __syncthreads();
    for (int e = base + t; e < end; e += 256) atomicAdd(&lh[dst[e] >> BUCK_SHIFT], 1);
    __syncthreads();
    for (int b = t; b < nb; b += 256) {
        int c = lh[b];
        lh[b] = c ? atomicAdd(&cursor[b], c) : 0;
    }
    __syncthreads();
    for (int e = base + t; e < end; e += 256) {
        int d = dst[e];
        int b = d >> BUCK_SHIFT;
        int pos = atomicAdd(&lh[b], 1);
        packed[pos] = (unsigned)src[e] | ((unsigned)(d & (BUCK_SIZE - 1)) << 18);
    }
}

// pass B: bucket -> exact CSR (contiguous writes within the bucket's col window)
__global__ void csr_kernel(const unsigned* __restrict__ packed, const int* __restrict__ boff,
                           const int* __restrict__ deg, int* __restrict__ rowptr,
                           int* __restrict__ col, int N) {
    __shared__ int scan[BUCK_SIZE];
    __shared__ int scur[BUCK_SIZE];
    int t = threadIdx.x, blk = blockIdx.x;
    int i = (blk << BUCK_SHIFT) + t;
    int d = (i < N) ? deg[i] : 0;
    scan[t] = d;
    __syncthreads();
    for (int off = 1; off < 256; off <<= 1) {
        int v = (t >= off) ? scan[t - off] : 0;
        __syncthreads();
        scan[t] += v;
        __syncthreads();
    }
    int b0 = boff[blk];
    int start = b0 + scan[t] - d;      // exclusive
    if (i < N) rowptr[i] = start;
    scur[t] = start;
    __syncthreads();
    int eend = boff[blk + 1];
    for (int e = b0 + t; e < eend; e += 256) {
        unsigned k = packed[e];
        int pos = atomicAdd(&scur[k >> 18], 1);
        col[pos] = (int)(k & 0x3FFFFu);
    }
}

// ---------------- z0 = dinv * (x @ W_in), fp16 ----------------

__global__ void z0_kernel(const float* __restrict__ x, const float* __restrict__ W,
                          const float* __restrict__ dinv, __half* __restrict__ z, int n) {
    __shared__ float sW[F_IN * DIM];
    int t = threadIdx.x;
#pragma unroll
    for (int j = 0; j < 4; ++j) sW[t + j * 256] = W[t + j * 256];
    __syncthreads();
    int idx = blockIdx.x * 256 + t;
    if (idx >= n * 2) return;
    int node = idx >> 1, p = idx & 1;
    float acc[8] = {0, 0, 0, 0, 0, 0, 0, 0};
    const float4* xr = (const float4*)(x + (size_t)node * F_IN);
#pragma unroll
    for (int k4 = 0; k4 < 16; ++k4) {
        float4 xv = xr[k4];
        float c[4] = { xv.x, xv.y, xv.z, xv.w };
#pragma unroll
        for (int cc = 0; cc < 4; ++cc) {
            const float* wr = &sW[(k4 * 4 + cc) * DIM + p * 8];
#pragma unroll
            for (int j = 0; j < 8; ++j) acc[j] += c[cc] * wr[j];
        }
    }
    float di = dinv[node];
    __half2 o[4];
#pragma unroll
    for (int m = 0; m < 4; ++m) o[m] = __floats2half2_rn(di * acc[2 * m], di * acc[2 * m + 1]);
    *(float4*)(z + (size_t)node * DIM + p * 8) = *(float4*)o;
}

// ---------------- gather + fused epilogue ----------------
// 2 lanes per node; lane p owns features [8p, 8p+8).
// mode 0: zout = fp16( di*(r + b) ),  r = di*(acc)          (layer 0)
// mode 1: hp   = r @ Wa + ba  (fp32) + BN partial sums      (hidden layers)
// mode 3: o1   = relu(r @ Wa + ba); o2 = relu(r @ Wb + bb)  (heads)

__launch_bounds__(256)
__global__ void gather_kernel(const int* __restrict__ rowptr, const int* __restrict__ deg,
                              const int* __restrict__ col, const __half* __restrict__ z,
                              const float* __restrict__ dinv,
                              const float* __restrict__ Wa, const float* __restrict__ Wb,
                              const float* __restrict__ ba, const float* __restrict__ bb,
                              float* __restrict__ o1, float* __restrict__ o2,
                              __half* __restrict__ zout, float* __restrict__ bnsum,
                              int N, int mode) {
    __shared__ float sW[544];            // Wa[256] Wb[256] ba[16] bb[16]
    __shared__ float s1[256 * 9];        // BN partial sums (stride 9: bank spread)
    __shared__ float s2[256 * 9];
    int t = threadIdx.x;
    if (mode != 0) {
        sW[t] = Wa[t];
        if (mode == 3) sW[256 + t] = Wb[t];
    }
    if (t < 16) {
        sW[512 + t] = ba[t];
        if (mode == 3) sW[528 + t] = bb[t];
    }
    __syncthreads();

    int idx = blockIdx.x * 256 + t;
    int node = idx >> 1, p = idx & 1;
    bool alive = node < N;
    float a[8] = {0, 0, 0, 0, 0, 0, 0, 0};
    float di = 0.f;
    if (alive) {
        const __half* zrow = z + ((size_t)node << 4) + (p << 3);
        float4 sv = *(const float4*)zrow;            // self loop
        const __half2* h2 = (const __half2*)&sv;
#pragma unroll
        for (int m = 0; m < 4; ++m) {
            float2 f = __half22float2(h2[m]);
            a[2 * m] = f.x; a[2 * m + 1] = f.y;
        }
        int start = rowptr[node], len = deg[node];
        for (int k = 0; k < len; ++k) {
            int s = col[start + k];
            float4 v = *(const float4*)(z + ((size_t)s << 4) + (p << 3));
            const __half2* vh = (const __half2*)&v;
#pragma unroll
            for (int m = 0; m < 4; ++m) {
                float2 f = __half22float2(vh[m]);
                a[2 * m] += f.x; a[2 * m + 1] += f.y;
            }
        }
        di = dinv[node];
    }
    float r[8];
#pragma unroll
    for (int j = 0; j < 8; ++j) r[j] = di * a[j];

    if (mode == 0) {
        if (alive) {
            __half2 o[4];
#pragma unroll
            for (int m = 0; m < 4; ++m)
                o[m] = __floats2half2_rn(di * (r[2 * m] + sW[512 + p * 8 + 2 * m]),
                                         di * (r[2 * m + 1] + sW[512 + p * 8 + 2 * m + 1]));
            *(float4*)(zout + ((size_t)node << 4) + (p << 3)) = *(float4*)o;
        }
        return;
    }

    if (mode == 1) {
        float part[16];
#pragma unroll
        for (int j = 0; j < 16; ++j) {
            float s = 0.f;
            const float* wr = &sW[(p * 8) * 16 + j];
#pragma unroll
            for (int f = 0; f < 8; ++f) s += r[f] * wr[f * 16];
            part[j] = s;
        }
#pragma unroll
        for (int j = 0; j < 16; ++j) part[j] += __shfl_xor(part[j], 1);
        float o[16];
#pragma unroll
        for (int j = 0; j < 16; ++j) o[j] = part[j] + sW[512 + j];
        if (alive) {
            float4 w0 = make_float4(o[p * 8 + 0], o[p * 8 + 1], o[p * 8 + 2], o[p * 8 + 3]);
            float4 w1 = make_float4(o[p * 8 + 4], o[p * 8 + 5], o[p * 8 + 6], o[p * 8 + 7]);
            float4* op = (float4*)(o1 + ((size_t)node << 4) + (p << 3));
            op[0] = w0; op[1] = w1;
        }
        // BN partial sums: lane contributes its owned 8 features
#pragma unroll
        for (int j = 0; j < 8; ++j) {
            float v = alive ? o[p * 8 + j] : 0.f;
            s1[t * 9 + j] = v;
            s2[t * 9 + j] = v * v;
        }
        __syncthreads();
        for (int st = 128; st >= 2; st >>= 1) {        // st even: parity (p) preserved
            if (t < st) {
#pragma unroll
                for (int j = 0; j < 8; ++j) {
                    s1[t * 9 + j] += s1[(t + st) * 9 + j];
                    s2[t * 9 + j] += s2[(t + st) * 9 + j];
                }
            }
            __syncthreads();
        }
        if (t < 2) {
#pragma unroll
            for (int j = 0; j < 8; ++j) {
                atomicAdd(&bnsum[t * 8 + j], s1[t * 9 + j]);
                atomicAdd(&bnsum[16 + t * 8 + j], s2[t * 9 + j]);
            }
        }
        return;
    }

    // mode 3: dual head
    {
        float pa[16], pb[16];
#pragma unroll
        for (int j = 0; j < 16; ++j) {
            float s = 0.f, c = 0.f;
            const float* wr = &sW[(p * 8) * 16 + j];
            const float* wr2 = &sW[256 + (p * 8) * 16 + j];
#pragma unroll
            for (int f = 0; f < 8; ++f) { s += r[f] * wr[f * 16]; c += r[f] * wr2[f * 16]; }
            pa[j] = s; pb[j] = c;
        }
#pragma unroll
        for (int j = 0; j < 16; ++j) {
            pa[j] += __shfl_xor(pa[j], 1);
            pb[j] += __shfl_xor(pb[j], 1);
        }
        if (alive) {
            float oa[8], ob[8];
#pragma unroll
            for (int j = 0; j < 8; ++j) {
                oa[j] = fmaxf(pa[p * 8 + j] + sW[512 + p * 8 + j], 0.f);
                ob[j] = fmaxf(pb[p * 8 + j] + sW[528 + p * 8 + j], 0.f);
            }
            float4* os = (float4*)(o1 + ((size_t)node << 4) + (p << 3));
            os[0] = make_float4(oa[0], oa[1], oa[2], oa[3]);
            os[1] = make_float4(oa[4], oa[5], oa[6], oa[7]);
            float4* oc = (float4*)(o2 + ((size_t)node << 4) + (p << 3));
            oc[0] = make_float4(ob[0], ob[1], ob[2], ob[3]);
            oc[1] = make_float4(ob[4], ob[5], ob[6], ob[7]);
        }
    }
}

// ---------------- BN apply + ReLU -> next z (fp16, pre-scaled by dinv) ----------------

__global__ void bn_relu_z_kernel(const float4* __restrict__ hp, const float* __restrict__ bnsum,
                                 const float* __restrict__ gamma, const float* __restrict__ beta,
                                 const float* __restrict__ dinv, __half* __restrict__ z, int n) {
    int idx = blockIdx.x * 256 + threadIdx.x;
    if (idx >= n * 4) return;
    int node = idx >> 2, q = idx & 3;
    float invN = 1.f / (float)n;
    float di = dinv[node];
    float4 v = hp[idx];
    float vv[4] = { v.x, v.y, v.z, v.w };
    float rr[4];
#pragma unroll
    for (int j = 0; j < 4; ++j) {
        int f = q * 4 + j;
        float mean = bnsum[f] * invN;
        float var = fmaxf(bnsum[16 + f] * invN - mean * mean, 0.f);
        rr[j] = di * fmaxf(gamma[f] * (vv[j] - mean) * rsqrtf(var + 1e-5f) + beta[f], 0.f);
    }
    __half2* zo = (__half2*)(z + (size_t)node * DIM + q * 4);
    zo[0] = __floats2half2_rn(rr[0], rr[1]);
    zo[1] = __floats2half2_rn(rr[2], rr[3]);
}

// ---------------- launcher ----------------

extern "C" void kernel_launch(void* const* d_in, const int* in_sizes, int n_in,
                              void* d_out, int out_size, void* d_ws, size_t ws_size,
                              hipStream_t stream) {
    (void)n_in; (void)out_size; (void)ws_size;
    const float* x      = (const float*)d_in[0];
    const int*   edge   = (const int*)d_in[1];
    const float* W_in   = (const float*)d_in[2];
    const float* b_in   = (const float*)d_in[3];
    const float* Ws     = (const float*)d_in[4];
    const float* bs     = (const float*)d_in[5];
    const float* gammas = (const float*)d_in[6];
    const float* betas  = (const float*)d_in[7];
    const float* W_sin  = (const float*)d_in[8];
    const float* b_sin  = (const float*)d_in[9];
    const float* W_cos  = (const float*)d_in[10];
    const float* b_cos  = (const float*)d_in[11];
    float* out = (float*)d_out;

    const int N = in_sizes[0] / F_IN;          // 200000
    const int E = in_sizes[1] / 2;             // 6400000
    const int L = in_sizes[4] / (DIM * DIM);   // 4
    const int nb = (N + BUCK_SIZE - 1) >> BUCK_SHIFT;   // 782
    const int* src = edge;
    const int* dst = edge + E;

    char* ws = (char*)d_ws;
    size_t off = 0;
    auto alloc = [&](size_t bytes) { char* p = ws + off; off += (bytes + 15) & ~size_t(15); return p; };
    int*      deg    = (int*)alloc((size_t)N * 4);
    float*    dinv   = (float*)alloc((size_t)N * 4);
    int*      ghist  = (int*)alloc((size_t)nb * 4);
    int*      boff   = (int*)alloc((size_t)(nb + 1) * 4);
    int*      cursor = (int*)alloc((size_t)nb * 4);
    int*      rowptr = (int*)alloc((size_t)N * 4);
    unsigned* packed = (unsigned*)alloc((size_t)E * 4);
    int*      col    = (int*)alloc((size_t)E * 4);
    __half*   zA     = (__half*)alloc((size_t)N * DIM * 2);
    __half*   zB     = (__half*)alloc((size_t)N * DIM * 2);
    float*    hp     = (float*)alloc((size_t)N * DIM * 4);
    float*    bnsum  = (float*)alloc(32 * 4 * (size_t)L);

    hipMemsetAsync(deg, 0, (size_t)N * 4, stream);
    hipMemsetAsync(bnsum, 0, 32 * 4 * (size_t)L, stream);

    deg_kernel<<<(E + 255) / 256, 256, 0, stream>>>(dst, deg, E);
    dinv_kernel<<<(N + 255) / 256, 256, 0, stream>>>(deg, dinv, N);
    ghist_kernel<<<nb, 256, 0, stream>>>(deg, ghist, N);
    scan_kernel<<<1, 256, 0, stream>>>(ghist, boff, cursor, nb, E);
    bin_kernel<<<(E + BIN_CHUNK - 1) / BIN_CHUNK, 256, 0, stream>>>(src, dst, cursor, packed, E, nb);
    csr_kernel<<<nb, 256, 0, stream>>>(packed, boff, deg, rowptr, col, N);

    const int ggrid = (N * 2 + 255) / 256;

    // layer 0
    z0_kernel<<<ggrid, 256, 0, stream>>>(x, W_in, dinv, zA, N);
    gather_kernel<<<ggrid, 256, 0, stream>>>(rowptr, deg, col, zA, dinv,
                                             nullptr, nullptr, b_in, nullptr,
                                             nullptr, nullptr, zB, nullptr, N, 0);
    __half* zc = zB;
    __half* zn = zA;

    // hidden layers
    for (int l = 0; l < L; ++l) {
        gather_kernel<<<ggrid, 256, 0, stream>>>(rowptr, deg, col, zc, dinv,
                                                 Ws + l * DIM * DIM, nullptr,
                                                 bs + l * DIM, nullptr,
                                                 hp, nullptr, nullptr, bnsum + 32 * l, N, 1);
        bn_relu_z_kernel<<<(N * 4 + 255) / 256, 256, 0, stream>>>(
            (const float4*)hp, bnsum + 32 * l, gammas + l * DIM, betas + l * DIM,
            dinv, zn, N);
        __half* tmp = zc; zc = zn; zn = tmp;
    }

    // heads: one shared aggregation, dual epilogue straight into d_out
    gather_kernel<<<ggrid, 256, 0, stream>>>(rowptr, deg, col, zc, dinv,
                                             W_sin, W_cos, b_sin, b_cos,
                                             out, out + (size_t)N * DIM, nullptr, nullptr, N, 3);
}

// Round 5
// 1320.117 us; speedup vs baseline: 3.4553x; 1.4084x over previous
//
#include <hip/hip_runtime.h>
#include <hip/hip_fp16.h>

// RNAGNN round 5: split-feature fp16 message tables (3.2 MB each -> fits one XCD L2),
// two gather passes per conv, 4 lanes/node, fused matmul/BN/head epilogues.
//   z = dinv ⊙ h  split as zlo (feats 0-7) / zhi (feats 8-15), fp16 16B rows
//   pass lo: rlo[i] = dinv[i]*(zlo[i] + Σ zlo[src])          (stored fp32)
//   pass hi: rhi likewise, then out = [rlo|rhi] @ W + b (+BN stats / ReLU heads)

#define DIM 16
#define F_IN 64
#define BUCK_SHIFT 8
#define BUCK_SIZE 256
#define MAXB 800
#define BIN_CHUNK 4096

// LDS weight layout: W[f][j] at q-block stride 65 (q=f>>2) -> 4 distinct banks per read
#define WA_OFF 0
#define WB_OFF 260
#define BA_OFF 520
#define BB_OFF 536
#define SW_SIZE 552
#define WIDX(f, j) ((((f) >> 2) * 65) + (((f) & 3) * 16) + (j))

// ---------------- degree + dinv ----------------

__global__ void deg_kernel(const int* __restrict__ dst, int* __restrict__ deg, int E) {
    int e = blockIdx.x * blockDim.x + threadIdx.x;
    if (e < E) atomicAdd(&deg[dst[e]], 1);
}

__global__ void dinv_kernel(const int* __restrict__ deg, float* __restrict__ dinv, int n) {
    int i = blockIdx.x * blockDim.x + threadIdx.x;
    if (i < n) dinv[i] = rsqrtf((float)(deg[i] + 1));  // +1 = self loop
}

// per-bucket edge counts (from deg)
__global__ void ghist_kernel(const int* __restrict__ deg, int* __restrict__ ghist, int N) {
    __shared__ int sd[BUCK_SIZE];
    int b = blockIdx.x, t = threadIdx.x;
    int i = (b << BUCK_SHIFT) + t;
    sd[t] = (i < N) ? deg[i] : 0;
    __syncthreads();
    for (int st = 128; st > 0; st >>= 1) {
        if (t < st) sd[t] += sd[t + st];
        __syncthreads();
    }
    if (t == 0) ghist[b] = sd[0];
}

// exclusive scan of ghist (nb <= 1024) -> boff, cursor
__global__ void scan_kernel(const int* __restrict__ ghist, int* __restrict__ boff,
                            int* __restrict__ cursor, int nb, int E) {
    __shared__ int sd[256];
    int t = threadIdx.x;
    const int CH = 4;
    int v[CH];
    int s = 0;
#pragma unroll
    for (int j = 0; j < CH; ++j) {
        int i = t * CH + j;
        v[j] = (i < nb) ? ghist[i] : 0;
        s += v[j];
    }
    sd[t] = s;
    __syncthreads();
    for (int off = 1; off < 256; off <<= 1) {
        int u = (t >= off) ? sd[t - off] : 0;
        __syncthreads();
        sd[t] += u;
        __syncthreads();
    }
    int excl = (t > 0) ? sd[t - 1] : 0;
#pragma unroll
    for (int j = 0; j < CH; ++j) {
        int i = t * CH + j;
        if (i < nb) { boff[i] = excl; cursor[i] = excl; excl += v[j]; }
    }
    if (t == 255) boff[nb] = E;
}

// pass A: bin edges into dst-range buckets; packed = src | (local_dst << 18)
__global__ void bin_kernel(const int* __restrict__ src, const int* __restrict__ dst,
                           int* __restrict__ cursor, unsigned* __restrict__ packed,
                           int E, int nb) {
    __shared__ int lh[MAXB];
    int t = threadIdx.x;
    int base = blockIdx.x * BIN_CHUNK;
    int end = min(base + BIN_CHUNK, E);
    for (int i = t; i < nb; i += 256) lh[i] = 0;
    __syncthreads();
    for (int e = base + t; e < end; e += 256) atomicAdd(&lh[dst[e] >> BUCK_SHIFT], 1);
    __syncthreads();
    for (int b = t; b < nb; b += 256) {
        int c = lh[b];
        lh[b] = c ? atomicAdd(&cursor[b], c) : 0;
    }
    __syncthreads();
    for (int e = base + t; e < end; e += 256) {
        int d = dst[e];
        int b = d >> BUCK_SHIFT;
        int pos = atomicAdd(&lh[b], 1);
        packed[pos] = (unsigned)src[e] | ((unsigned)(d & (BUCK_SIZE - 1)) << 18);
    }
}

// pass B: bucket -> exact CSR
__global__ void csr_kernel(const unsigned* __restrict__ packed, const int* __restrict__ boff,
                           const int* __restrict__ deg, int* __restrict__ rowptr,
                           int* __restrict__ col, int N) {
    __shared__ int scan[BUCK_SIZE];
    __shared__ int scur[BUCK_SIZE];
    int t = threadIdx.x, blk = blockIdx.x;
    int i = (blk << BUCK_SHIFT) + t;
    int d = (i < N) ? deg[i] : 0;
    scan[t] = d;
    __syncthreads();
    for (int off = 1; off < 256; off <<= 1) {
        int v = (t >= off) ? scan[t - off] : 0;
        __syncthreads();
        scan[t] += v;
        __syncthreads();
    }
    int b0 = boff[blk];
    int start = b0 + scan[t] - d;
    if (i < N) rowptr[i] = start;
    scur[t] = start;
    __syncthreads();
    int eend = boff[blk + 1];
    for (int e = b0 + t; e < eend; e += 256) {
        unsigned k = packed[e];
        int pos = atomicAdd(&scur[k >> 18], 1);
        col[pos] = (int)(k & 0x3FFFFu);
    }
}

// ---------------- z0 = dinv * (x @ W_in), split fp16 tables ----------------

__global__ void z0_kernel(const float* __restrict__ x, const float* __restrict__ W,
                          const float* __restrict__ dinv,
                          __half* __restrict__ zlo, __half* __restrict__ zhi, int n) {
    __shared__ float sW[F_IN * DIM];
    int t = threadIdx.x;
#pragma unroll
    for (int j = 0; j < 4; ++j) sW[t + j * 256] = W[t + j * 256];
    __syncthreads();
    int idx = blockIdx.x * 256 + t;
    if (idx >= n * 2) return;
    int node = idx >> 1, p = idx & 1;
    float acc[8] = {0, 0, 0, 0, 0, 0, 0, 0};
    const float4* xr = (const float4*)(x + (size_t)node * F_IN);
#pragma unroll
    for (int k4 = 0; k4 < 16; ++k4) {
        float4 xv = xr[k4];
        float c[4] = { xv.x, xv.y, xv.z, xv.w };
#pragma unroll
        for (int cc = 0; cc < 4; ++cc) {
            const float* wr = &sW[(k4 * 4 + cc) * DIM + p * 8];
#pragma unroll
            for (int j = 0; j < 8; ++j) acc[j] += c[cc] * wr[j];
        }
    }
    float di = dinv[node];
    __half2 o[4];
#pragma unroll
    for (int m = 0; m < 4; ++m) o[m] = __floats2half2_rn(di * acc[2 * m], di * acc[2 * m + 1]);
    __half* zt = p ? zhi : zlo;
    *(float4*)(zt + ((size_t)node << 3)) = *(float4*)o;
}

// ---------------- gather over one half-table (8 feats), 4 lanes/node ----------------
// MODE 10: store r (pass lo)
// MODE 0 : identity epilogue, znext = fp16(di*(r + b_slice))   (layer 0, per pass)
// MODE 1 : pass hi, full matmul -> o1 (pre-BN fp32) + BN partials -> bnsum replica
// MODE 3 : pass hi, dual matmul + ReLU -> o1, o2 (heads)

template <int MODE>
__launch_bounds__(256)
__global__ void gather8_kernel(const int* __restrict__ rowptr, const int* __restrict__ deg,
                               const int* __restrict__ col, const __half* __restrict__ zP,
                               const float* __restrict__ dinv, const float* __restrict__ rlo,
                               const float* __restrict__ Wa, const float* __restrict__ Wb,
                               const float* __restrict__ ba, const float* __restrict__ bb,
                               float* __restrict__ o1, float* __restrict__ o2,
                               __half* __restrict__ znext, float* __restrict__ rout,
                               float* __restrict__ bnsum, int N, int pass) {
    __shared__ float sW[SW_SIZE];
    __shared__ float sred[4][32];
    int t = threadIdx.x;
    if (MODE == 1 || MODE == 3) {
        int f = t >> 4, j = t & 15;
        sW[WA_OFF + WIDX(f, j)] = Wa[t];
        if (MODE == 3) sW[WB_OFF + WIDX(f, j)] = Wb[t];
        if (t < 16) {
            sW[BA_OFF + t] = ba[t];
            if (MODE == 3) sW[BB_OFF + t] = bb[t];
        }
        __syncthreads();
    } else if (MODE == 0) {
        if (t < 8) sW[BA_OFF + t] = ba[pass * 8 + t];
        __syncthreads();
    }

    int idx = blockIdx.x * 256 + t;
    int node = idx >> 2, q = idx & 3;
    bool alive = node < N;
    float a[8] = {0, 0, 0, 0, 0, 0, 0, 0};
    float di = 0.f;
    if (alive) {
        di = dinv[node];
        int start = rowptr[node], len = deg[node];
        for (int k = q; k < len; k += 4) {
            int s = col[start + k];
            float4 v = *(const float4*)(zP + ((size_t)s << 3));
            const __half2* vh = (const __half2*)&v;
#pragma unroll
            for (int m = 0; m < 4; ++m) {
                float2 f2 = __half22float2(vh[m]);
                a[2 * m] += f2.x; a[2 * m + 1] += f2.y;
            }
        }
    }
#pragma unroll
    for (int j = 0; j < 8; ++j) {
        a[j] += __shfl_xor(a[j], 1);
        a[j] += __shfl_xor(a[j], 2);
    }
    if (alive) {   // self loop (same value added by all 4 lanes -> stays consistent)
        float4 sv = *(const float4*)(zP + ((size_t)node << 3));
        const __half2* sh = (const __half2*)&sv;
#pragma unroll
        for (int m = 0; m < 4; ++m) {
            float2 f2 = __half22float2(sh[m]);
            a[2 * m] += f2.x; a[2 * m + 1] += f2.y;
        }
    }
    float r[8];
#pragma unroll
    for (int j = 0; j < 8; ++j) r[j] = di * a[j];

    if (MODE == 10) {
        if (alive && q < 2) {
            float4 w = (q == 0) ? make_float4(r[0], r[1], r[2], r[3])
                                : make_float4(r[4], r[5], r[6], r[7]);
            *(float4*)(rout + ((size_t)node << 3) + (q << 2)) = w;
        }
        return;
    }
    if (MODE == 0) {
        if (alive && q == 0) {
            __half2 o[4];
#pragma unroll
            for (int m = 0; m < 4; ++m)
                o[m] = __floats2half2_rn(di * (r[2 * m] + sW[BA_OFF + 2 * m]),
                                         di * (r[2 * m + 1] + sW[BA_OFF + 2 * m + 1]));
            *(float4*)(znext + ((size_t)node << 3)) = *(float4*)o;
        }
        return;
    }

    // MODE 1 / 3: assemble r16 across the quad; lane q owns input feats [4q, 4q+4)
    float rc[4];
    if (q < 2) {
        float4 v = alive ? ((const float4*)(rlo + ((size_t)node << 3)))[q]
                         : make_float4(0.f, 0.f, 0.f, 0.f);
        rc[0] = v.x; rc[1] = v.y; rc[2] = v.z; rc[3] = v.w;
    } else {
#pragma unroll
        for (int i = 0; i < 4; ++i) rc[i] = r[(q - 2) * 4 + i];
    }
    int fb = q * 4;
    float pa[16];
#pragma unroll
    for (int j = 0; j < 16; ++j)
        pa[j] = rc[0] * sW[WA_OFF + WIDX(fb, j)]     + rc[1] * sW[WA_OFF + WIDX(fb + 1, j)]
              + rc[2] * sW[WA_OFF + WIDX(fb + 2, j)] + rc[3] * sW[WA_OFF + WIDX(fb + 3, j)];
#pragma unroll
    for (int j = 0; j < 16; ++j) {
        pa[j] += __shfl_xor(pa[j], 1);
        pa[j] += __shfl_xor(pa[j], 2);
    }

    if (MODE == 1) {
        float o[4];
#pragma unroll
        for (int i = 0; i < 4; ++i) o[i] = pa[fb + i] + sW[BA_OFF + fb + i];
        if (alive)
            *(float4*)(o1 + ((size_t)node << 4) + fb) = make_float4(o[0], o[1], o[2], o[3]);
        // BN partials: lane owns output feats [fb, fb+4)
        float s[4], ss[4];
#pragma unroll
        for (int i = 0; i < 4; ++i) {
            float v = alive ? o[i] : 0.f;
            s[i] = v; ss[i] = v * v;
        }
#pragma unroll
        for (int m = 4; m <= 32; m <<= 1) {
#pragma unroll
            for (int i = 0; i < 4; ++i) {
                s[i] += __shfl_xor(s[i], m);
                ss[i] += __shfl_xor(ss[i], m);
            }
        }
        int lane = t & 63, wave = t >> 6;
        if (lane < 4) {
#pragma unroll
            for (int i = 0; i < 4; ++i) {
                sred[wave][lane * 4 + i] = s[i];
                sred[wave][16 + lane * 4 + i] = ss[i];
            }
        }
        __syncthreads();
        if (t < 32) {
            float v = sred[0][t] + sred[1][t] + sred[2][t] + sred[3][t];
            atomicAdd(&bnsum[(blockIdx.x & 7) * 32 + t], v);
        }
        return;
    }

    // MODE 3: dual heads
    {
        float pb[16];
#pragma unroll
        for (int j = 0; j < 16; ++j)
            pb[j] = rc[0] * sW[WB_OFF + WIDX(fb, j)]     + rc[1] * sW[WB_OFF + WIDX(fb + 1, j)]
                  + rc[2] * sW[WB_OFF + WIDX(fb + 2, j)] + rc[3] * sW[WB_OFF + WIDX(fb + 3, j)];
#pragma unroll
        for (int j = 0; j < 16; ++j) {
            pb[j] += __shfl_xor(pb[j], 1);
            pb[j] += __shfl_xor(pb[j], 2);
        }
        if (alive) {
            float oa[4], ob[4];
#pragma unroll
            for (int i = 0; i < 4; ++i) {
                oa[i] = fmaxf(pa[fb + i] + sW[BA_OFF + fb + i], 0.f);
                ob[i] = fmaxf(pb[fb + i] + sW[BB_OFF + fb + i], 0.f);
            }
            *(float4*)(o1 + ((size_t)node << 4) + fb) = make_float4(oa[0], oa[1], oa[2], oa[3]);
            *(float4*)(o2 + ((size_t)node << 4) + fb) = make_float4(ob[0], ob[1], ob[2], ob[3]);
        }
    }
}

// ---------------- BN finalize (8 replicas -> scale/shift) ----------------

__global__ void bnfin_kernel(const float* __restrict__ bnsum, const float* __restrict__ gamma,
                             const float* __restrict__ beta, float* __restrict__ ssout, int n) {
    int t = threadIdx.x;
    if (t >= 16) return;
    float s = 0.f, sq = 0.f;
#pragma unroll
    for (int rep = 0; rep < 8; ++rep) {
        s += bnsum[rep * 32 + t];
        sq += bnsum[rep * 32 + 16 + t];
    }
    float invN = 1.f / (float)n;
    float mean = s * invN;
    float var = fmaxf(sq * invN - mean * mean, 0.f);
    float scale = gamma[t] * rsqrtf(var + 1e-5f);
    ssout[t] = scale;
    ssout[16 + t] = beta[t] - mean * scale;
}

// ---------------- BN apply + ReLU -> next split z tables ----------------

__global__ void bn_relu_z_kernel(const float* __restrict__ hp, const float* __restrict__ ss,
                                 const float* __restrict__ dinv,
                                 __half* __restrict__ zlo, __half* __restrict__ zhi, int n) {
    int idx = blockIdx.x * 256 + threadIdx.x;
    if (idx >= n * 2) return;
    int node = idx >> 1, p = idx & 1;
    float di = dinv[node];
    const float4* hr = (const float4*)(hp + ((size_t)node << 4) + p * 8);
    float4 v0 = hr[0], v1 = hr[1];
    float vv[8] = { v0.x, v0.y, v0.z, v0.w, v1.x, v1.y, v1.z, v1.w };
    __half2 o[4];
#pragma unroll
    for (int m = 0; m < 4; ++m) {
        int f0 = p * 8 + 2 * m;
        float r0 = di * fmaxf(vv[2 * m] * ss[f0] + ss[16 + f0], 0.f);
        float r1 = di * fmaxf(vv[2 * m + 1] * ss[f0 + 1] + ss[16 + f0 + 1], 0.f);
        o[m] = __floats2half2_rn(r0, r1);
    }
    __half* zt = p ? zhi : zlo;
    *(float4*)(zt + ((size_t)node << 3)) = *(float4*)o;
}

// ---------------- launcher ----------------

extern "C" void kernel_launch(void* const* d_in, const int* in_sizes, int n_in,
                              void* d_out, int out_size, void* d_ws, size_t ws_size,
                              hipStream_t stream) {
    (void)n_in; (void)out_size; (void)ws_size;
    const float* x      = (const float*)d_in[0];
    const int*   edge   = (const int*)d_in[1];
    const float* W_in   = (const float*)d_in[2];
    const float* b_in   = (const float*)d_in[3];
    const float* Ws     = (const float*)d_in[4];
    const float* bs     = (const float*)d_in[5];
    const float* gammas = (const float*)d_in[6];
    const float* betas  = (const float*)d_in[7];
    const float* W_sin  = (const float*)d_in[8];
    const float* b_sin  = (const float*)d_in[9];
    const float* W_cos  = (const float*)d_in[10];
    const float* b_cos  = (const float*)d_in[11];
    float* out = (float*)d_out;

    const int N = in_sizes[0] / F_IN;          // 200000
    const int E = in_sizes[1] / 2;             // 6400000
    const int L = in_sizes[4] / (DIM * DIM);   // 4
    const int nb = (N + BUCK_SIZE - 1) >> BUCK_SHIFT;   // 782
    const int* src = edge;
    const int* dst = edge + E;

    char* ws = (char*)d_ws;
    size_t off = 0;
    auto alloc = [&](size_t bytes) { char* p = ws + off; off += (bytes + 15) & ~size_t(15); return p; };
    int*      deg    = (int*)alloc((size_t)N * 4);
    float*    dinv   = (float*)alloc((size_t)N * 4);
    int*      ghist  = (int*)alloc((size_t)nb * 4);
    int*      boff   = (int*)alloc((size_t)(nb + 1) * 4);
    int*      cursor = (int*)alloc((size_t)nb * 4);
    int*      rowptr = (int*)alloc((size_t)N * 4);
    unsigned* packed = (unsigned*)alloc((size_t)E * 4);
    int*      col    = (int*)alloc((size_t)E * 4);
    __half*   zAlo   = (__half*)alloc((size_t)N * 8 * 2);
    __half*   zAhi   = (__half*)alloc((size_t)N * 8 * 2);
    __half*   zBlo   = (__half*)alloc((size_t)N * 8 * 2);
    __half*   zBhi   = (__half*)alloc((size_t)N * 8 * 2);
    float*    rbuf   = (float*)alloc((size_t)N * 8 * 4);
    float*    hp     = (float*)alloc((size_t)N * DIM * 4);
    float*    bnsum  = (float*)alloc((size_t)L * 256 * 4);   // 8 replicas x 32 per layer
    float*    ssbuf  = (float*)alloc((size_t)L * 32 * 4);

    hipMemsetAsync(deg, 0, (size_t)N * 4, stream);
    hipMemsetAsync(bnsum, 0, (size_t)L * 256 * 4, stream);

    deg_kernel<<<(E + 255) / 256, 256, 0, stream>>>(dst, deg, E);
    dinv_kernel<<<(N + 255) / 256, 256, 0, stream>>>(deg, dinv, N);
    ghist_kernel<<<nb, 256, 0, stream>>>(deg, ghist, N);
    scan_kernel<<<1, 256, 0, stream>>>(ghist, boff, cursor, nb, E);
    bin_kernel<<<(E + BIN_CHUNK - 1) / BIN_CHUNK, 256, 0, stream>>>(src, dst, cursor, packed, E, nb);
    csr_kernel<<<nb, 256, 0, stream>>>(packed, boff, deg, rowptr, col, N);

    const int G = (N * 4 + 255) / 256;         // gather grid (4 lanes/node)

    // layer 0: z0 then identity-epilogue passes (halves independent)
    z0_kernel<<<(N * 2 + 255) / 256, 256, 0, stream>>>(x, W_in, dinv, zAlo, zAhi, N);
    gather8_kernel<0><<<G, 256, 0, stream>>>(rowptr, deg, col, zAlo, dinv, nullptr,
                                             nullptr, nullptr, b_in, nullptr,
                                             nullptr, nullptr, zBlo, nullptr, nullptr, N, 0);
    gather8_kernel<0><<<G, 256, 0, stream>>>(rowptr, deg, col, zAhi, dinv, nullptr,
                                             nullptr, nullptr, b_in, nullptr,
                                             nullptr, nullptr, zBhi, nullptr, nullptr, N, 1);
    __half *clo = zBlo, *chi = zBhi, *nlo = zAlo, *nhi = zAhi;

    for (int l = 0; l < L; ++l) {
        gather8_kernel<10><<<G, 256, 0, stream>>>(rowptr, deg, col, clo, dinv, nullptr,
                                                  nullptr, nullptr, nullptr, nullptr,
                                                  nullptr, nullptr, nullptr, rbuf, nullptr, N, 0);
        gather8_kernel<1><<<G, 256, 0, stream>>>(rowptr, deg, col, chi, dinv, rbuf,
                                                 Ws + l * DIM * DIM, nullptr,
                                                 bs + l * DIM, nullptr,
                                                 hp, nullptr, nullptr, nullptr,
                                                 bnsum + l * 256, N, 1);
        bnfin_kernel<<<1, 64, 0, stream>>>(bnsum + l * 256, gammas + l * DIM,
                                           betas + l * DIM, ssbuf + l * 32, N);
        bn_relu_z_kernel<<<(N * 2 + 255) / 256, 256, 0, stream>>>(hp, ssbuf + l * 32, dinv,
                                                                  nlo, nhi, N);
        __half* t1 = clo; clo = nlo; nlo = t1;
        __half* t2 = chi; chi = nhi; nhi = t2;
    }

    // heads: shared aggregation, dual epilogue into d_out
    gather8_kernel<10><<<G, 256, 0, stream>>>(rowptr, deg, col, clo, dinv, nullptr,
                                              nullptr, nullptr, nullptr, nullptr,
                                              nullptr, nullptr, nullptr, rbuf, nullptr, N, 0);
    gather8_kernel<3><<<G, 256, 0, stream>>>(rowptr, deg, col, chi, dinv, rbuf,
                                             W_sin, W_cos, b_sin, b_cos,
                                             out, out + (size_t)N * DIM, nullptr, nullptr,
                                             nullptr, N, 1);
}

// Round 6
// 967.926 us; speedup vs baseline: 4.7125x; 1.3639x over previous
//
#include <hip/hip_runtime.h>
#include <hip/hip_fp16.h>

// RNAGNN round 6: deg_kernel eliminated (LDS-histogram ghist + degrees derived in
// csr_kernel). Split-feature fp16 message tables (3.2 MB -> one XCD L2), two gather
// passes per conv, fused matmul/BN/head epilogues.

#define DIM 16
#define F_IN 64
#define BUCK_SHIFT 8
#define BUCK_SIZE 256
#define MAXB 800
#define BIN_CHUNK 16384

// LDS weight layout: W[f][j] at q-block stride 65 (q=f>>2) -> 4 distinct banks per read
#define WA_OFF 0
#define WB_OFF 260
#define BA_OFF 520
#define BB_OFF 536
#define SW_SIZE 552
#define WIDX(f, j) ((((f) >> 2) * 65) + (((f) & 3) * 16) + (j))

// ---------------- per-bucket edge histogram (replaces deg_kernel) ----------------

__global__ void hist_kernel(const int* __restrict__ dst, int* __restrict__ ghist,
                            int E, int nb) {
    __shared__ int lh[MAXB];
    int t = threadIdx.x;
    for (int i = t; i < nb; i += 256) lh[i] = 0;
    __syncthreads();
    int base = blockIdx.x * BIN_CHUNK;
    int end = min(base + BIN_CHUNK, E);
    for (int e = base + t; e < end; e += 256) atomicAdd(&lh[dst[e] >> BUCK_SHIFT], 1);
    __syncthreads();
    for (int b = t; b < nb; b += 256) {
        int c = lh[b];
        if (c) atomicAdd(&ghist[b], c);
    }
}

// exclusive scan of ghist (nb <= 1024) -> boff, cursor
__global__ void scan_kernel(const int* __restrict__ ghist, int* __restrict__ boff,
                            int* __restrict__ cursor, int nb, int E) {
    __shared__ int sd[256];
    int t = threadIdx.x;
    const int CH = 4;
    int v[CH];
    int s = 0;
#pragma unroll
    for (int j = 0; j < CH; ++j) {
        int i = t * CH + j;
        v[j] = (i < nb) ? ghist[i] : 0;
        s += v[j];
    }
    sd[t] = s;
    __syncthreads();
    for (int off = 1; off < 256; off <<= 1) {
        int u = (t >= off) ? sd[t - off] : 0;
        __syncthreads();
        sd[t] += u;
        __syncthreads();
    }
    int excl = (t > 0) ? sd[t - 1] : 0;
#pragma unroll
    for (int j = 0; j < CH; ++j) {
        int i = t * CH + j;
        if (i < nb) { boff[i] = excl; cursor[i] = excl; excl += v[j]; }
    }
    if (t == 255) boff[nb] = E;
}

// pass A: bin edges into dst-range buckets; packed = src | (local_dst << 18)
__global__ void bin_kernel(const int* __restrict__ src, const int* __restrict__ dst,
                           int* __restrict__ cursor, unsigned* __restrict__ packed,
                           int E, int nb) {
    __shared__ int lh[MAXB];
    int t = threadIdx.x;
    int base = blockIdx.x * BIN_CHUNK;
    int end = min(base + BIN_CHUNK, E);
    for (int i = t; i < nb; i += 256) lh[i] = 0;
    __syncthreads();
    for (int e = base + t; e < end; e += 256) atomicAdd(&lh[dst[e] >> BUCK_SHIFT], 1);
    __syncthreads();
    for (int b = t; b < nb; b += 256) {
        int c = lh[b];
        lh[b] = c ? atomicAdd(&cursor[b], c) : 0;
    }
    __syncthreads();
    for (int e = base + t; e < end; e += 256) {
        int d = dst[e];
        int b = d >> BUCK_SHIFT;
        int pos = atomicAdd(&lh[b], 1);
        packed[pos] = (unsigned)src[e] | ((unsigned)(d & (BUCK_SIZE - 1)) << 18);
    }
}

// pass B: bucket -> exact CSR; also derives per-node degree, rowptr (N+1), dinv
__global__ void csr_kernel(const unsigned* __restrict__ packed, const int* __restrict__ boff,
                           int* __restrict__ rowptr, float* __restrict__ dinv,
                           int* __restrict__ col, int N, int E) {
    __shared__ int cnt[BUCK_SIZE];
    __shared__ int spos[BUCK_SIZE];
    __shared__ int scur[BUCK_SIZE];
    int t = threadIdx.x, blk = blockIdx.x;
    cnt[t] = 0;
    __syncthreads();
    int b0 = boff[blk], e1 = boff[blk + 1];
    for (int e = b0 + t; e < e1; e += 256) atomicAdd(&cnt[packed[e] >> 18], 1);
    __syncthreads();
    int d = cnt[t];
    spos[t] = d;
    __syncthreads();
    for (int off = 1; off < 256; off <<= 1) {
        int v = (t >= off) ? spos[t - off] : 0;
        __syncthreads();
        spos[t] += v;
        __syncthreads();
    }
    int start = b0 + spos[t] - d;
    int i = (blk << BUCK_SHIFT) + t;
    if (i < N) {
        rowptr[i] = start;
        dinv[i] = rsqrtf((float)(d + 1));       // +1 = self loop
        if (i == N - 1) rowptr[N] = E;
    }
    scur[t] = start;
    __syncthreads();
    for (int e = b0 + t; e < e1; e += 256) {
        unsigned k = packed[e];
        int pos = atomicAdd(&scur[k >> 18], 1);
        col[pos] = (int)(k & 0x3FFFFu);
    }
}

// ---------------- z0 = dinv * (x @ W_in), split fp16 tables ----------------

__global__ void z0_kernel(const float* __restrict__ x, const float* __restrict__ W,
                          const float* __restrict__ dinv,
                          __half* __restrict__ zlo, __half* __restrict__ zhi, int n) {
    __shared__ float sW[F_IN * DIM];
    int t = threadIdx.x;
#pragma unroll
    for (int j = 0; j < 4; ++j) sW[t + j * 256] = W[t + j * 256];
    __syncthreads();
    int idx = blockIdx.x * 256 + t;
    if (idx >= n * 2) return;
    int node = idx >> 1, p = idx & 1;
    float acc[8] = {0, 0, 0, 0, 0, 0, 0, 0};
    const float4* xr = (const float4*)(x + (size_t)node * F_IN);
#pragma unroll
    for (int k4 = 0; k4 < 16; ++k4) {
        float4 xv = xr[k4];
        float c[4] = { xv.x, xv.y, xv.z, xv.w };
#pragma unroll
        for (int cc = 0; cc < 4; ++cc) {
            const float* wr = &sW[(k4 * 4 + cc) * DIM + p * 8];
#pragma unroll
            for (int j = 0; j < 8; ++j) acc[j] += c[cc] * wr[j];
        }
    }
    float di = dinv[node];
    __half2 o[4];
#pragma unroll
    for (int m = 0; m < 4; ++m) o[m] = __floats2half2_rn(di * acc[2 * m], di * acc[2 * m + 1]);
    __half* zt = p ? zhi : zlo;
    *(float4*)(zt + ((size_t)node << 3)) = *(float4*)o;
}

// ---------------- gather over one half-table (8 feats), 4 lanes/node ----------------
// MODE 10: store r (pass lo)
// MODE 0 : identity epilogue, znext = fp16(di*(r + b_slice))   (layer 0, per pass)
// MODE 1 : pass hi, full matmul -> o1 (pre-BN fp32) + BN partials -> bnsum replica
// MODE 3 : pass hi, dual matmul + ReLU -> o1, o2 (heads)

template <int MODE>
__launch_bounds__(256)
__global__ void gather8_kernel(const int* __restrict__ rowptr, const int* __restrict__ col,
                               const __half* __restrict__ zP, const float* __restrict__ dinv,
                               const float* __restrict__ rlo,
                               const float* __restrict__ Wa, const float* __restrict__ Wb,
                               const float* __restrict__ ba, const float* __restrict__ bb,
                               float* __restrict__ o1, float* __restrict__ o2,
                               __half* __restrict__ znext, float* __restrict__ rout,
                               float* __restrict__ bnsum, int N, int pass) {
    __shared__ float sW[SW_SIZE];
    __shared__ float sred[4][32];
    int t = threadIdx.x;
    if (MODE == 1 || MODE == 3) {
        int f = t >> 4, j = t & 15;
        sW[WA_OFF + WIDX(f, j)] = Wa[t];
        if (MODE == 3) sW[WB_OFF + WIDX(f, j)] = Wb[t];
        if (t < 16) {
            sW[BA_OFF + t] = ba[t];
            if (MODE == 3) sW[BB_OFF + t] = bb[t];
        }
        __syncthreads();
    } else if (MODE == 0) {
        if (t < 8) sW[BA_OFF + t] = ba[pass * 8 + t];
        __syncthreads();
    }

    int idx = blockIdx.x * 256 + t;
    int node = idx >> 2, q = idx & 3;
    bool alive = node < N;
    float a[8] = {0, 0, 0, 0, 0, 0, 0, 0};
    float di = 0.f;
    if (alive) {
        di = dinv[node];
        int start = rowptr[node];
        int len = rowptr[node + 1] - start;
        int k = q;
        for (; k + 4 < len; k += 8) {          // 2 edges in flight per lane
            int s0 = col[start + k];
            int s1 = col[start + k + 4];
            float4 v0 = *(const float4*)(zP + ((size_t)s0 << 3));
            float4 v1 = *(const float4*)(zP + ((size_t)s1 << 3));
            const __half2* h0 = (const __half2*)&v0;
            const __half2* h1 = (const __half2*)&v1;
#pragma unroll
            for (int m = 0; m < 4; ++m) {
                float2 f0 = __half22float2(h0[m]);
                float2 f1 = __half22float2(h1[m]);
                a[2 * m] += f0.x + f1.x;
                a[2 * m + 1] += f0.y + f1.y;
            }
        }
        if (k < len) {
            int s = col[start + k];
            float4 v = *(const float4*)(zP + ((size_t)s << 3));
            const __half2* vh = (const __half2*)&v;
#pragma unroll
            for (int m = 0; m < 4; ++m) {
                float2 f2 = __half22float2(vh[m]);
                a[2 * m] += f2.x; a[2 * m + 1] += f2.y;
            }
        }
    }
#pragma unroll
    for (int j = 0; j < 8; ++j) {
        a[j] += __shfl_xor(a[j], 1);
        a[j] += __shfl_xor(a[j], 2);
    }
    if (alive) {   // self loop (same value added by all 4 lanes -> stays consistent)
        float4 sv = *(const float4*)(zP + ((size_t)node << 3));
        const __half2* sh = (const __half2*)&sv;
#pragma unroll
        for (int m = 0; m < 4; ++m) {
            float2 f2 = __half22float2(sh[m]);
            a[2 * m] += f2.x; a[2 * m + 1] += f2.y;
        }
    }
    float r[8];
#pragma unroll
    for (int j = 0; j < 8; ++j) r[j] = di * a[j];

    if (MODE == 10) {
        if (alive && q < 2) {
            float4 w = (q == 0) ? make_float4(r[0], r[1], r[2], r[3])
                                : make_float4(r[4], r[5], r[6], r[7]);
            *(float4*)(rout + ((size_t)node << 3) + (q << 2)) = w;
        }
        return;
    }
    if (MODE == 0) {
        if (alive && q == 0) {
            __half2 o[4];
#pragma unroll
            for (int m = 0; m < 4; ++m)
                o[m] = __floats2half2_rn(di * (r[2 * m] + sW[BA_OFF + 2 * m]),
                                         di * (r[2 * m + 1] + sW[BA_OFF + 2 * m + 1]));
            *(float4*)(znext + ((size_t)node << 3)) = *(float4*)o;
        }
        return;
    }

    // MODE 1 / 3: assemble r16 across the quad; lane q owns input feats [4q, 4q+4)
    float rc[4];
    if (q < 2) {
        float4 v = alive ? ((const float4*)(rlo + ((size_t)node << 3)))[q]
                         : make_float4(0.f, 0.f, 0.f, 0.f);
        rc[0] = v.x; rc[1] = v.y; rc[2] = v.z; rc[3] = v.w;
    } else {
#pragma unroll
        for (int i = 0; i < 4; ++i) rc[i] = r[(q - 2) * 4 + i];
    }
    int fb = q * 4;
    float pa[16];
#pragma unroll
    for (int j = 0; j < 16; ++j)
        pa[j] = rc[0] * sW[WA_OFF + WIDX(fb, j)]     + rc[1] * sW[WA_OFF + WIDX(fb + 1, j)]
              + rc[2] * sW[WA_OFF + WIDX(fb + 2, j)] + rc[3] * sW[WA_OFF + WIDX(fb + 3, j)];
#pragma unroll
    for (int j = 0; j < 16; ++j) {
        pa[j] += __shfl_xor(pa[j], 1);
        pa[j] += __shfl_xor(pa[j], 2);
    }

    if (MODE == 1) {
        float o[4];
#pragma unroll
        for (int i = 0; i < 4; ++i) o[i] = pa[fb + i] + sW[BA_OFF + fb + i];
        if (alive)
            *(float4*)(o1 + ((size_t)node << 4) + fb) = make_float4(o[0], o[1], o[2], o[3]);
        float s[4], ss[4];
#pragma unroll
        for (int i = 0; i < 4; ++i) {
            float v = alive ? o[i] : 0.f;
            s[i] = v; ss[i] = v * v;
        }
#pragma unroll
        for (int m = 4; m <= 32; m <<= 1) {
#pragma unroll
            for (int i = 0; i < 4; ++i) {
                s[i] += __shfl_xor(s[i], m);
                ss[i] += __shfl_xor(ss[i], m);
            }
        }
        int lane = t & 63, wave = t >> 6;
        if (lane < 4) {
#pragma unroll
            for (int i = 0; i < 4; ++i) {
                sred[wave][lane * 4 + i] = s[i];
                sred[wave][16 + lane * 4 + i] = ss[i];
            }
        }
        __syncthreads();
        if (t < 32) {
            float v = sred[0][t] + sred[1][t] + sred[2][t] + sred[3][t];
            atomicAdd(&bnsum[(blockIdx.x & 7) * 32 + t], v);
        }
        return;
    }

    // MODE 3: dual heads
    {
        float pb[16];
#pragma unroll
        for (int j = 0; j < 16; ++j)
            pb[j] = rc[0] * sW[WB_OFF + WIDX(fb, j)]     + rc[1] * sW[WB_OFF + WIDX(fb + 1, j)]
                  + rc[2] * sW[WB_OFF + WIDX(fb + 2, j)] + rc[3] * sW[WB_OFF + WIDX(fb + 3, j)];
#pragma unroll
        for (int j = 0; j < 16; ++j) {
            pb[j] += __shfl_xor(pb[j], 1);
            pb[j] += __shfl_xor(pb[j], 2);
        }
        if (alive) {
            float oa[4], ob[4];
#pragma unroll
            for (int i = 0; i < 4; ++i) {
                oa[i] = fmaxf(pa[fb + i] + sW[BA_OFF + fb + i], 0.f);
                ob[i] = fmaxf(pb[fb + i] + sW[BB_OFF + fb + i], 0.f);
            }
            *(float4*)(o1 + ((size_t)node << 4) + fb) = make_float4(oa[0], oa[1], oa[2], oa[3]);
            *(float4*)(o2 + ((size_t)node << 4) + fb) = make_float4(ob[0], ob[1], ob[2], ob[3]);
        }
    }
}

// ---------------- BN finalize (8 replicas -> scale/shift) ----------------

__global__ void bnfin_kernel(const float* __restrict__ bnsum, const float* __restrict__ gamma,
                             const float* __restrict__ beta, float* __restrict__ ssout, int n) {
    int t = threadIdx.x;
    if (t >= 16) return;
    float s = 0.f, sq = 0.f;
#pragma unroll
    for (int rep = 0; rep < 8; ++rep) {
        s += bnsum[rep * 32 + t];
        sq += bnsum[rep * 32 + 16 + t];
    }
    float invN = 1.f / (float)n;
    float mean = s * invN;
    float var = fmaxf(sq * invN - mean * mean, 0.f);
    float scale = gamma[t] * rsqrtf(var + 1e-5f);
    ssout[t] = scale;
    ssout[16 + t] = beta[t] - mean * scale;
}

// ---------------- BN apply + ReLU -> next split z tables ----------------

__global__ void bn_relu_z_kernel(const float* __restrict__ hp, const float* __restrict__ ss,
                                 const float* __restrict__ dinv,
                                 __half* __restrict__ zlo, __half* __restrict__ zhi, int n) {
    int idx = blockIdx.x * 256 + threadIdx.x;
    if (idx >= n * 2) return;
    int node = idx >> 1, p = idx & 1;
    float di = dinv[node];
    const float4* hr = (const float4*)(hp + ((size_t)node << 4) + p * 8);
    float4 v0 = hr[0], v1 = hr[1];
    float vv[8] = { v0.x, v0.y, v0.z, v0.w, v1.x, v1.y, v1.z, v1.w };
    __half2 o[4];
#pragma unroll
    for (int m = 0; m < 4; ++m) {
        int f0 = p * 8 + 2 * m;
        float r0 = di * fmaxf(vv[2 * m] * ss[f0] + ss[16 + f0], 0.f);
        float r1 = di * fmaxf(vv[2 * m + 1] * ss[f0 + 1] + ss[16 + f0 + 1], 0.f);
        o[m] = __floats2half2_rn(r0, r1);
    }
    __half* zt = p ? zhi : zlo;
    *(float4*)(zt + ((size_t)node << 3)) = *(float4*)o;
}

// ---------------- launcher ----------------

extern "C" void kernel_launch(void* const* d_in, const int* in_sizes, int n_in,
                              void* d_out, int out_size, void* d_ws, size_t ws_size,
                              hipStream_t stream) {
    (void)n_in; (void)out_size; (void)ws_size;
    const float* x      = (const float*)d_in[0];
    const int*   edge   = (const int*)d_in[1];
    const float* W_in   = (const float*)d_in[2];
    const float* b_in   = (const float*)d_in[3];
    const float* Ws     = (const float*)d_in[4];
    const float* bs     = (const float*)d_in[5];
    const float* gammas = (const float*)d_in[6];
    const float* betas  = (const float*)d_in[7];
    const float* W_sin  = (const float*)d_in[8];
    const float* b_sin  = (const float*)d_in[9];
    const float* W_cos  = (const float*)d_in[10];
    const float* b_cos  = (const float*)d_in[11];
    float* out = (float*)d_out;

    const int N = in_sizes[0] / F_IN;          // 200000
    const int E = in_sizes[1] / 2;             // 6400000
    const int L = in_sizes[4] / (DIM * DIM);   // 4
    const int nb = (N + BUCK_SIZE - 1) >> BUCK_SHIFT;   // 782
    const int* src = edge;
    const int* dst = edge + E;

    char* ws = (char*)d_ws;
    size_t off = 0;
    auto alloc = [&](size_t bytes) { char* p = ws + off; off += (bytes + 15) & ~size_t(15); return p; };
    float*    dinv   = (float*)alloc((size_t)N * 4);
    int*      ghist  = (int*)alloc((size_t)nb * 4);
    int*      boff   = (int*)alloc((size_t)(nb + 1) * 4);
    int*      cursor = (int*)alloc((size_t)nb * 4);
    int*      rowptr = (int*)alloc((size_t)(N + 1) * 4);
    unsigned* packed = (unsigned*)alloc((size_t)E * 4);
    int*      col    = (int*)alloc((size_t)E * 4);
    __half*   zAlo   = (__half*)alloc((size_t)N * 8 * 2);
    __half*   zAhi   = (__half*)alloc((size_t)N * 8 * 2);
    __half*   zBlo   = (__half*)alloc((size_t)N * 8 * 2);
    __half*   zBhi   = (__half*)alloc((size_t)N * 8 * 2);
    float*    rbuf   = (float*)alloc((size_t)N * 8 * 4);
    float*    hp     = (float*)alloc((size_t)N * DIM * 4);
    float*    bnsum  = (float*)alloc((size_t)L * 256 * 4);   // 8 replicas x 32 per layer
    float*    ssbuf  = (float*)alloc((size_t)L * 32 * 4);

    hipMemsetAsync(ghist, 0, (size_t)nb * 4, stream);
    hipMemsetAsync(bnsum, 0, (size_t)L * 256 * 4, stream);

    const int nchunk = (E + BIN_CHUNK - 1) / BIN_CHUNK;
    hist_kernel<<<nchunk, 256, 0, stream>>>(dst, ghist, E, nb);
    scan_kernel<<<1, 256, 0, stream>>>(ghist, boff, cursor, nb, E);
    bin_kernel<<<nchunk, 256, 0, stream>>>(src, dst, cursor, packed, E, nb);
    csr_kernel<<<nb, 256, 0, stream>>>(packed, boff, rowptr, dinv, col, N, E);

    const int G = (N * 4 + 255) / 256;         // gather grid (4 lanes/node)

    // layer 0: z0 then identity-epilogue passes (halves independent)
    z0_kernel<<<(N * 2 + 255) / 256, 256, 0, stream>>>(x, W_in, dinv, zAlo, zAhi, N);
    gather8_kernel<0><<<G, 256, 0, stream>>>(rowptr, col, zAlo, dinv, nullptr,
                                             nullptr, nullptr, b_in, nullptr,
                                             nullptr, nullptr, zBlo, nullptr, nullptr, N, 0);
    gather8_kernel<0><<<G, 256, 0, stream>>>(rowptr, col, zAhi, dinv, nullptr,
                                             nullptr, nullptr, b_in, nullptr,
                                             nullptr, nullptr, zBhi, nullptr, nullptr, N, 1);
    __half *clo = zBlo, *chi = zBhi, *nlo = zAlo, *nhi = zAhi;

    for (int l = 0; l < L; ++l) {
        gather8_kernel<10><<<G, 256, 0, stream>>>(rowptr, col, clo, dinv, nullptr,
                                                  nullptr, nullptr, nullptr, nullptr,
                                                  nullptr, nullptr, nullptr, rbuf, nullptr, N, 0);
        gather8_kernel<1><<<G, 256, 0, stream>>>(rowptr, col, chi, dinv, rbuf,
                                                 Ws + l * DIM * DIM, nullptr,
                                                 bs + l * DIM, nullptr,
                                                 hp, nullptr, nullptr, nullptr,
                                                 bnsum + l * 256, N, 1);
        bnfin_kernel<<<1, 64, 0, stream>>>(bnsum + l * 256, gammas + l * DIM,
                                           betas + l * DIM, ssbuf + l * 32, N);
        bn_relu_z_kernel<<<(N * 2 + 255) / 256, 256, 0, stream>>>(hp, ssbuf + l * 32, dinv,
                                                                  nlo, nhi, N);
        __half* t1 = clo; clo = nlo; nlo = t1;
        __half* t2 = chi; chi = nhi; nhi = t2;
    }

    // heads: shared aggregation, dual epilogue into d_out
    gather8_kernel<10><<<G, 256, 0, stream>>>(rowptr, col, clo, dinv, nullptr,
                                              nullptr, nullptr, nullptr, nullptr,
                                              nullptr, nullptr, nullptr, rbuf, nullptr, N, 0);
    gather8_kernel<3><<<G, 256, 0, stream>>>(rowptr, col, chi, dinv, rbuf,
                                             W_sin, W_cos, b_sin, b_cos,
                                             out, out + (size_t)N * DIM, nullptr, nullptr,
                                             nullptr, N, 1);
}

// Round 7
// 888.486 us; speedup vs baseline: 5.1339x; 1.0894x over previous
//
#include <hip/hip_runtime.h>
#include <hip/hip_fp16.h>

// RNAGNN round 7: 1024-node buckets (dense bin writes), 8-lane-per-node gather
// (shorter dependent-load chains), split-feature fp16 tables (3.2 MB -> one XCD L2).

#define DIM 16
#define F_IN 64
#define BUCK_SHIFT 10
#define BUCK_SIZE 1024
#define MAXB 256            // nb = ceil(200000/1024) = 196
#define BIN_CHUNK 16384

// LDS weight layout: W[f][j] at f*17+j -> lanes with distinct f hit distinct banks
#define WA_OFF 0
#define WB_OFF 272
#define BA_OFF 544
#define BB_OFF 560
#define SW_SIZE 576
#define WIDX(f, j) ((f) * 17 + (j))

// ---------------- per-bucket edge histogram ----------------

__global__ void hist_kernel(const int* __restrict__ dst, int* __restrict__ ghist,
                            int E, int nb) {
    __shared__ int lh[MAXB];
    int t = threadIdx.x;
    for (int i = t; i < nb; i += 256) lh[i] = 0;
    __syncthreads();
    int base = blockIdx.x * BIN_CHUNK;
    int end = min(base + BIN_CHUNK, E);
    for (int e = base + t; e < end; e += 256) atomicAdd(&lh[dst[e] >> BUCK_SHIFT], 1);
    __syncthreads();
    for (int b = t; b < nb; b += 256) {
        int c = lh[b];
        if (c) atomicAdd(&ghist[b], c);
    }
}

// exclusive scan of ghist (nb <= 256) -> boff, cursor
__global__ void scan_kernel(const int* __restrict__ ghist, int* __restrict__ boff,
                            int* __restrict__ cursor, int nb, int E) {
    __shared__ int sd[256];
    int t = threadIdx.x;
    int v = (t < nb) ? ghist[t] : 0;
    sd[t] = v;
    __syncthreads();
    for (int off = 1; off < 256; off <<= 1) {
        int u = (t >= off) ? sd[t - off] : 0;
        __syncthreads();
        sd[t] += u;
        __syncthreads();
    }
    if (t < nb) {
        int excl = sd[t] - v;
        boff[t] = excl;
        cursor[t] = excl;
    }
    if (t == 255) boff[nb] = E;
}

// pass A: bin edges into dst-range buckets; packed = src | (local_dst << 18)
__global__ void bin_kernel(const int* __restrict__ src, const int* __restrict__ dst,
                           int* __restrict__ cursor, unsigned* __restrict__ packed,
                           int E, int nb) {
    __shared__ int lh[MAXB];
    int t = threadIdx.x;
    int base = blockIdx.x * BIN_CHUNK;
    int end = min(base + BIN_CHUNK, E);
    for (int i = t; i < nb; i += 256) lh[i] = 0;
    __syncthreads();
    for (int e = base + t; e < end; e += 256) atomicAdd(&lh[dst[e] >> BUCK_SHIFT], 1);
    __syncthreads();
    for (int b = t; b < nb; b += 256) {
        int c = lh[b];
        lh[b] = c ? atomicAdd(&cursor[b], c) : 0;
    }
    __syncthreads();
    for (int e = base + t; e < end; e += 256) {
        int d = dst[e];
        int b = d >> BUCK_SHIFT;
        int pos = atomicAdd(&lh[b], 1);
        packed[pos] = (unsigned)src[e] | ((unsigned)(d & (BUCK_SIZE - 1)) << 18);
    }
}

// pass B: bucket -> exact CSR; derives degree, rowptr (N+1), dinv. 1024 threads.
__global__ void csr_kernel(const unsigned* __restrict__ packed, const int* __restrict__ boff,
                           int* __restrict__ rowptr, float* __restrict__ dinv,
                           int* __restrict__ col, int N, int E) {
    __shared__ int cnt[BUCK_SIZE];
    __shared__ int sd[BUCK_SIZE];
    __shared__ int scur[BUCK_SIZE];
    int t = threadIdx.x, blk = blockIdx.x;
    cnt[t] = 0;
    __syncthreads();
    int b0 = boff[blk], e1 = boff[blk + 1];
    for (int e = b0 + t; e < e1; e += 1024) atomicAdd(&cnt[packed[e] >> 18], 1);
    __syncthreads();
    int d = cnt[t];
    sd[t] = d;
    __syncthreads();
    for (int off = 1; off < 1024; off <<= 1) {
        int v = (t >= off) ? sd[t - off] : 0;
        __syncthreads();
        sd[t] += v;
        __syncthreads();
    }
    int start = b0 + sd[t] - d;
    int i = (blk << BUCK_SHIFT) + t;
    if (i < N) {
        rowptr[i] = start;
        dinv[i] = rsqrtf((float)(d + 1));       // +1 = self loop
        if (i == N - 1) rowptr[N] = E;
    }
    scur[t] = start;
    __syncthreads();
    for (int e = b0 + t; e < e1; e += 1024) {
        unsigned k = packed[e];
        int pos = atomicAdd(&scur[k >> 18], 1);
        col[pos] = (int)(k & 0x3FFFFu);
    }
}

// ---------------- z0 = dinv * (x @ W_in), split fp16 tables ----------------

__global__ void z0_kernel(const float* __restrict__ x, const float* __restrict__ W,
                          const float* __restrict__ dinv,
                          __half* __restrict__ zlo, __half* __restrict__ zhi, int n) {
    __shared__ float sW[F_IN * DIM];
    int t = threadIdx.x;
#pragma unroll
    for (int j = 0; j < 4; ++j) sW[t + j * 256] = W[t + j * 256];
    __syncthreads();
    int idx = blockIdx.x * 256 + t;
    if (idx >= n * 2) return;
    int node = idx >> 1, p = idx & 1;
    float acc[8] = {0, 0, 0, 0, 0, 0, 0, 0};
    const float4* xr = (const float4*)(x + (size_t)node * F_IN);
#pragma unroll
    for (int k4 = 0; k4 < 16; ++k4) {
        float4 xv = xr[k4];
        float c[4] = { xv.x, xv.y, xv.z, xv.w };
#pragma unroll
        for (int cc = 0; cc < 4; ++cc) {
            const float* wr = &sW[(k4 * 4 + cc) * DIM + p * 8];
#pragma unroll
            for (int j = 0; j < 8; ++j) acc[j] += c[cc] * wr[j];
        }
    }
    float di = dinv[node];
    __half2 o[4];
#pragma unroll
    for (int m = 0; m < 4; ++m) o[m] = __floats2half2_rn(di * acc[2 * m], di * acc[2 * m + 1]);
    __half* zt = p ? zhi : zlo;
    *(float4*)(zt + ((size_t)node << 3)) = *(float4*)o;
}

// ---------------- gather over one half-table (8 feats), 8 lanes/node ----------------
// MODE 10: store r (pass lo)
// MODE 0 : identity epilogue, znext = fp16(di*(r + b_slice))   (layer 0, per pass)
// MODE 1 : pass hi, full matmul -> o1 (pre-BN fp32) + BN partials -> bnsum replica
// MODE 3 : pass hi, dual matmul + ReLU -> o1, o2 (heads)

template <int MODE>
__launch_bounds__(256)
__global__ void gather8_kernel(const int* __restrict__ rowptr, const int* __restrict__ col,
                               const __half* __restrict__ zP, const float* __restrict__ dinv,
                               const float* __restrict__ rlo,
                               const float* __restrict__ Wa, const float* __restrict__ Wb,
                               const float* __restrict__ ba, const float* __restrict__ bb,
                               float* __restrict__ o1, float* __restrict__ o2,
                               __half* __restrict__ znext, float* __restrict__ rout,
                               float* __restrict__ bnsum, int N, int pass) {
    __shared__ float sW[SW_SIZE];
    __shared__ float sred[4][32];
    int t = threadIdx.x;
    if (MODE == 1 || MODE == 3) {
        int f = t >> 4, j = t & 15;
        sW[WA_OFF + WIDX(f, j)] = Wa[t];
        if (MODE == 3) sW[WB_OFF + WIDX(f, j)] = Wb[t];
        if (t < 16) {
            sW[BA_OFF + t] = ba[t];
            if (MODE == 3) sW[BB_OFF + t] = bb[t];
        }
        __syncthreads();
    } else if (MODE == 0) {
        if (t < 8) sW[BA_OFF + t] = ba[pass * 8 + t];
        __syncthreads();
    }

    int idx = blockIdx.x * 256 + t;
    int node = idx >> 3, o = idx & 7;          // 8 lanes per node
    bool alive = node < N;
    float a[8] = {0, 0, 0, 0, 0, 0, 0, 0};
    float di = 0.f;
    if (alive) {
        di = dinv[node];
        int start = rowptr[node];
        int len = rowptr[node + 1] - start;
        int k = o;
        for (; k + 8 < len; k += 16) {         // 2 edges in flight per lane
            int s0 = col[start + k];
            int s1 = col[start + k + 8];
            float4 v0 = *(const float4*)(zP + ((size_t)s0 << 3));
            float4 v1 = *(const float4*)(zP + ((size_t)s1 << 3));
            const __half2* h0 = (const __half2*)&v0;
            const __half2* h1 = (const __half2*)&v1;
#pragma unroll
            for (int m = 0; m < 4; ++m) {
                float2 f0 = __half22float2(h0[m]);
                float2 f1 = __half22float2(h1[m]);
                a[2 * m] += f0.x + f1.x;
                a[2 * m + 1] += f0.y + f1.y;
            }
        }
        if (k < len) {
            int s = col[start + k];
            float4 v = *(const float4*)(zP + ((size_t)s << 3));
            const __half2* vh = (const __half2*)&v;
#pragma unroll
            for (int m = 0; m < 4; ++m) {
                float2 f2 = __half22float2(vh[m]);
                a[2 * m] += f2.x; a[2 * m + 1] += f2.y;
            }
        }
    }
#pragma unroll
    for (int j = 0; j < 8; ++j) {
        a[j] += __shfl_xor(a[j], 1);
        a[j] += __shfl_xor(a[j], 2);
        a[j] += __shfl_xor(a[j], 4);
    }
    if (alive) {   // self loop (all 8 lanes add same value -> consistent)
        float4 sv = *(const float4*)(zP + ((size_t)node << 3));
        const __half2* sh = (const __half2*)&sv;
#pragma unroll
        for (int m = 0; m < 4; ++m) {
            float2 f2 = __half22float2(sh[m]);
            a[2 * m] += f2.x; a[2 * m + 1] += f2.y;
        }
    }
    float r[8];
#pragma unroll
    for (int j = 0; j < 8; ++j) r[j] = di * a[j];

    if (MODE == 10) {
        if (alive && o < 2) {
            float4 w = (o == 0) ? make_float4(r[0], r[1], r[2], r[3])
                                : make_float4(r[4], r[5], r[6], r[7]);
            *(float4*)(rout + ((size_t)node << 3) + (o << 2)) = w;
        }
        return;
    }
    if (MODE == 0) {
        if (alive && o == 0) {
            __half2 ov[4];
#pragma unroll
            for (int m = 0; m < 4; ++m)
                ov[m] = __floats2half2_rn(di * (r[2 * m] + sW[BA_OFF + 2 * m]),
                                          di * (r[2 * m + 1] + sW[BA_OFF + 2 * m + 1]));
            *(float4*)(znext + ((size_t)node << 3)) = *(float4*)ov;
        }
        return;
    }

    // MODE 1 / 3: lane o owns input feats {2o, 2o+1}; o<4 from rlo, o>=4 from local r
    float rc0, rc1;
    if (o < 4) {
        float2 v = alive ? *(const float2*)(rlo + ((size_t)node << 3) + 2 * o)
                         : make_float2(0.f, 0.f);
        rc0 = v.x; rc1 = v.y;
    } else {
        rc0 = r[2 * (o - 4)]; rc1 = r[2 * (o - 4) + 1];
        if (!alive) { rc0 = 0.f; rc1 = 0.f; }
    }
    int f0 = 2 * o;
    float pa[16];
#pragma unroll
    for (int j = 0; j < 16; ++j)
        pa[j] = rc0 * sW[WA_OFF + WIDX(f0, j)] + rc1 * sW[WA_OFF + WIDX(f0 + 1, j)];
#pragma unroll
    for (int j = 0; j < 16; ++j) {
        pa[j] += __shfl_xor(pa[j], 1);
        pa[j] += __shfl_xor(pa[j], 2);
        pa[j] += __shfl_xor(pa[j], 4);
    }

    if (MODE == 1) {
        float o0 = pa[2 * o] + sW[BA_OFF + 2 * o];
        float o1v = pa[2 * o + 1] + sW[BA_OFF + 2 * o + 1];
        if (alive)
            *(float2*)(o1 + ((size_t)node << 4) + 2 * o) = make_float2(o0, o1v);
        float s0 = alive ? o0 : 0.f, s1 = alive ? o1v : 0.f;
        float q0 = s0 * s0, q1 = s1 * s1;
#pragma unroll
        for (int m = 8; m <= 32; m <<= 1) {
            s0 += __shfl_xor(s0, m); s1 += __shfl_xor(s1, m);
            q0 += __shfl_xor(q0, m); q1 += __shfl_xor(q1, m);
        }
        int lane = t & 63, wave = t >> 6;
        if (lane < 8) {
            sred[wave][2 * lane] = s0;
            sred[wave][2 * lane + 1] = s1;
            sred[wave][16 + 2 * lane] = q0;
            sred[wave][16 + 2 * lane + 1] = q1;
        }
        __syncthreads();
        if (t < 32) {
            float v = sred[0][t] + sred[1][t] + sred[2][t] + sred[3][t];
            atomicAdd(&bnsum[(blockIdx.x & 7) * 32 + t], v);
        }
        return;
    }

    // MODE 3: dual heads
    {
        float pb[16];
#pragma unroll
        for (int j = 0; j < 16; ++j)
            pb[j] = rc0 * sW[WB_OFF + WIDX(f0, j)] + rc1 * sW[WB_OFF + WIDX(f0 + 1, j)];
#pragma unroll
        for (int j = 0; j < 16; ++j) {
            pb[j] += __shfl_xor(pb[j], 1);
            pb[j] += __shfl_xor(pb[j], 2);
            pb[j] += __shfl_xor(pb[j], 4);
        }
        if (alive) {
            float oa0 = fmaxf(pa[2 * o] + sW[BA_OFF + 2 * o], 0.f);
            float oa1 = fmaxf(pa[2 * o + 1] + sW[BA_OFF + 2 * o + 1], 0.f);
            float ob0 = fmaxf(pb[2 * o] + sW[BB_OFF + 2 * o], 0.f);
            float ob1 = fmaxf(pb[2 * o + 1] + sW[BB_OFF + 2 * o + 1], 0.f);
            *(float2*)(o1 + ((size_t)node << 4) + 2 * o) = make_float2(oa0, oa1);
            *(float2*)(o2 + ((size_t)node << 4) + 2 * o) = make_float2(ob0, ob1);
        }
    }
}

// ---------------- BN finalize (8 replicas -> scale/shift) ----------------

__global__ void bnfin_kernel(const float* __restrict__ bnsum, const float* __restrict__ gamma,
                             const float* __restrict__ beta, float* __restrict__ ssout, int n) {
    int t = threadIdx.x;
    if (t >= 16) return;
    float s = 0.f, sq = 0.f;
#pragma unroll
    for (int rep = 0; rep < 8; ++rep) {
        s += bnsum[rep * 32 + t];
        sq += bnsum[rep * 32 + 16 + t];
    }
    float invN = 1.f / (float)n;
    float mean = s * invN;
    float var = fmaxf(sq * invN - mean * mean, 0.f);
    float scale = gamma[t] * rsqrtf(var + 1e-5f);
    ssout[t] = scale;
    ssout[16 + t] = beta[t] - mean * scale;
}

// ---------------- BN apply + ReLU -> next split z tables ----------------

__global__ void bn_relu_z_kernel(const float* __restrict__ hp, const float* __restrict__ ss,
                                 const float* __restrict__ dinv,
                                 __half* __restrict__ zlo, __half* __restrict__ zhi, int n) {
    int idx = blockIdx.x * 256 + threadIdx.x;
    if (idx >= n * 2) return;
    int node = idx >> 1, p = idx & 1;
    float di = dinv[node];
    const float4* hr = (const float4*)(hp + ((size_t)node << 4) + p * 8);
    float4 v0 = hr[0], v1 = hr[1];
    float vv[8] = { v0.x, v0.y, v0.z, v0.w, v1.x, v1.y, v1.z, v1.w };
    __half2 o[4];
#pragma unroll
    for (int m = 0; m < 4; ++m) {
        int f0 = p * 8 + 2 * m;
        float r0 = di * fmaxf(vv[2 * m] * ss[f0] + ss[16 + f0], 0.f);
        float r1 = di * fmaxf(vv[2 * m + 1] * ss[f0 + 1] + ss[16 + f0 + 1], 0.f);
        o[m] = __floats2half2_rn(r0, r1);
    }
    __half* zt = p ? zhi : zlo;
    *(float4*)(zt + ((size_t)node << 3)) = *(float4*)o;
}

// ---------------- launcher ----------------

extern "C" void kernel_launch(void* const* d_in, const int* in_sizes, int n_in,
                              void* d_out, int out_size, void* d_ws, size_t ws_size,
                              hipStream_t stream) {
    (void)n_in; (void)out_size; (void)ws_size;
    const float* x      = (const float*)d_in[0];
    const int*   edge   = (const int*)d_in[1];
    const float* W_in   = (const float*)d_in[2];
    const float* b_in   = (const float*)d_in[3];
    const float* Ws     = (const float*)d_in[4];
    const float* bs     = (const float*)d_in[5];
    const float* gammas = (const float*)d_in[6];
    const float* betas  = (const float*)d_in[7];
    const float* W_sin  = (const float*)d_in[8];
    const float* b_sin  = (const float*)d_in[9];
    const float* W_cos  = (const float*)d_in[10];
    const float* b_cos  = (const float*)d_in[11];
    float* out = (float*)d_out;

    const int N = in_sizes[0] / F_IN;          // 200000
    const int E = in_sizes[1] / 2;             // 6400000
    const int L = in_sizes[4] / (DIM * DIM);   // 4
    const int nb = (N + BUCK_SIZE - 1) >> BUCK_SHIFT;   // 196
    const int* src = edge;
    const int* dst = edge + E;

    char* ws = (char*)d_ws;
    size_t off = 0;
    auto alloc = [&](size_t bytes) { char* p = ws + off; off += (bytes + 15) & ~size_t(15); return p; };
    float*    dinv   = (float*)alloc((size_t)N * 4);
    int*      ghist  = (int*)alloc((size_t)nb * 4);
    int*      boff   = (int*)alloc((size_t)(nb + 1) * 4);
    int*      cursor = (int*)alloc((size_t)nb * 4);
    int*      rowptr = (int*)alloc((size_t)(N + 1) * 4);
    unsigned* packed = (unsigned*)alloc((size_t)E * 4);
    int*      col    = (int*)alloc((size_t)E * 4);
    __half*   zAlo   = (__half*)alloc((size_t)N * 8 * 2);
    __half*   zAhi   = (__half*)alloc((size_t)N * 8 * 2);
    __half*   zBlo   = (__half*)alloc((size_t)N * 8 * 2);
    __half*   zBhi   = (__half*)alloc((size_t)N * 8 * 2);
    float*    rbuf   = (float*)alloc((size_t)N * 8 * 4);
    float*    hp     = (float*)alloc((size_t)N * DIM * 4);
    float*    bnsum  = (float*)alloc((size_t)L * 256 * 4);   // 8 replicas x 32 per layer
    float*    ssbuf  = (float*)alloc((size_t)L * 32 * 4);

    hipMemsetAsync(ghist, 0, (size_t)nb * 4, stream);
    hipMemsetAsync(bnsum, 0, (size_t)L * 256 * 4, stream);

    const int nchunk = (E + BIN_CHUNK - 1) / BIN_CHUNK;
    hist_kernel<<<nchunk, 256, 0, stream>>>(dst, ghist, E, nb);
    scan_kernel<<<1, 256, 0, stream>>>(ghist, boff, cursor, nb, E);
    bin_kernel<<<nchunk, 256, 0, stream>>>(src, dst, cursor, packed, E, nb);
    csr_kernel<<<nb, 1024, 0, stream>>>(packed, boff, rowptr, dinv, col, N, E);

    const int G = (N * 8 + 255) / 256;         // gather grid (8 lanes/node)

    // layer 0: z0 then identity-epilogue passes (halves independent)
    z0_kernel<<<(N * 2 + 255) / 256, 256, 0, stream>>>(x, W_in, dinv, zAlo, zAhi, N);
    gather8_kernel<0><<<G, 256, 0, stream>>>(rowptr, col, zAlo, dinv, nullptr,
                                             nullptr, nullptr, b_in, nullptr,
                                             nullptr, nullptr, zBlo, nullptr, nullptr, N, 0);
    gather8_kernel<0><<<G, 256, 0, stream>>>(rowptr, col, zAhi, dinv, nullptr,
                                             nullptr, nullptr, b_in, nullptr,
                                             nullptr, nullptr, zBhi, nullptr, nullptr, N, 1);
    __half *clo = zBlo, *chi = zBhi, *nlo = zAlo, *nhi = zAhi;

    for (int l = 0; l < L; ++l) {
        gather8_kernel<10><<<G, 256, 0, stream>>>(rowptr, col, clo, dinv, nullptr,
                                                  nullptr, nullptr, nullptr, nullptr,
                                                  nullptr, nullptr, nullptr, rbuf, nullptr, N, 0);
        gather8_kernel<1><<<G, 256, 0, stream>>>(rowptr, col, chi, dinv, rbuf,
                                                 Ws + l * DIM * DIM, nullptr,
                                                 bs + l * DIM, nullptr,
                                                 hp, nullptr, nullptr, nullptr,
                                                 bnsum + l * 256, N, 1);
        bnfin_kernel<<<1, 64, 0, stream>>>(bnsum + l * 256, gammas + l * DIM,
                                           betas + l * DIM, ssbuf + l * 32, N);
        bn_relu_z_kernel<<<(N * 2 + 255) / 256, 256, 0, stream>>>(hp, ssbuf + l * 32, dinv,
                                                                  nlo, nhi, N);
        __half* t1 = clo; clo = nlo; nlo = t1;
        __half* t2 = chi; chi = nhi; nhi = t2;
    }

    // heads: shared aggregation, dual epilogue into d_out
    gather8_kernel<10><<<G, 256, 0, stream>>>(rowptr, col, clo, dinv, nullptr,
                                              nullptr, nullptr, nullptr, nullptr,
                                              nullptr, nullptr, nullptr, rbuf, nullptr, N, 0);
    gather8_kernel<3><<<G, 256, 0, stream>>>(rowptr, col, chi, dinv, rbuf,
                                             W_sin, W_cos, b_sin, b_cos,
                                             out, out + (size_t)N * DIM, nullptr, nullptr,
                                             nullptr, N, 1);
}